// Round 1
// baseline (336.614 us; speedup 1.0000x reference)
//
#include <hip/hip_runtime.h>
#include <hip/hip_bf16.h>
#include <math.h>

#define NV 100000
#define NE_N 100000
#define NEDGE 250000
#define NEG 0.2f
#define LN_EPS 1e-5f

typedef __bf16 bf16_t;
typedef __bf16 bf16x8 __attribute__((ext_vector_type(8)));
typedef float f32x4 __attribute__((ext_vector_type(4)));

__device__ inline unsigned short f2bfu(float f) {
    return __builtin_bit_cast(unsigned short, (__bf16)f);
}
__device__ inline float bfu2f(unsigned short u) {
    return (float)__builtin_bit_cast(__bf16, u);
}
__device__ inline float blo(unsigned w) { return __uint_as_float(w << 16); }
__device__ inline float bhi(unsigned w) { return __uint_as_float(w & 0xffff0000u); }
__device__ inline float lrelu(float x) { return x > 0.f ? x : NEG * x; }
__device__ inline unsigned pk2(float a, float b) {
    return (unsigned)f2bfu(a) | ((unsigned)f2bfu(b) << 16);
}

// async global->LDS, 16B per lane; LDS dest is wave-uniform base + lane*16
__device__ __forceinline__ void gload_lds16(const bf16_t* g, unsigned short* l) {
    __builtin_amdgcn_global_load_lds(
        (const __attribute__((address_space(1))) unsigned int*)g,
        (__attribute__((address_space(3))) unsigned int*)l,
        16, 0, 0);
}

// ---------------------------------------------------------------------------
// prep: pack W matrices into bf16 A-fragment order:
//   pack[((ksq)*N + col)*8 + j] = W[ksq*8 + j][col],  ksq = 0..15 (K=128)
// ---------------------------------------------------------------------------
__global__ __launch_bounds__(256) void prep_kernel(
    const float* __restrict__ Wsrc, const float* __restrict__ Wdst,
    const float* __restrict__ Wp, bf16_t* __restrict__ pS,
    bf16_t* __restrict__ pD, bf16_t* __restrict__ pP)
{
    int t = blockIdx.x * 256 + threadIdx.x;
    if (t < 8192) {
        int ksq = t >> 9, col = t & 511;
#pragma unroll
        for (int j = 0; j < 8; ++j)
            pS[(size_t)t * 8 + j] = (bf16_t)Wsrc[(ksq * 8 + j) * 512 + col];
    } else if (t < 16384) {
        int g = t - 8192;
        int ksq = g >> 9, col = g & 511;
#pragma unroll
        for (int j = 0; j < 8; ++j)
            pD[(size_t)g * 8 + j] = (bf16_t)Wdst[(ksq * 8 + j) * 512 + col];
    } else if (t < 18432) {
        int g = t - 16384;
        int ksq = g >> 7, col = g & 127;
#pragma unroll
        for (int j = 0; j < 8; ++j)
            pP[(size_t)g * 8 + j] = (bf16_t)Wp[(ksq * 8 + j) * 128 + col];
    }
}

// ---------------------------------------------------------------------------
// CSR build kernels
// ---------------------------------------------------------------------------
__global__ __launch_bounds__(256) void count_kernel(
    const int* __restrict__ dst, int* __restrict__ deg)
{
    int t = blockIdx.x * 256 + threadIdx.x;
    if (t < NEDGE) atomicAdd(&deg[dst[t]], 1);
}

__global__ __launch_bounds__(256) void scan1_kernel(
    const int* __restrict__ deg, int* __restrict__ offs, int* __restrict__ bsum)
{
    __shared__ int s[256];
    int i = blockIdx.x * 256 + threadIdx.x;
    int v = (i < NE_N) ? deg[i] : 0;
    s[threadIdx.x] = v;
    __syncthreads();
    for (int off = 1; off < 256; off <<= 1) {
        int t_ = (threadIdx.x >= off) ? s[threadIdx.x - off] : 0;
        __syncthreads();
        s[threadIdx.x] += t_;
        __syncthreads();
    }
    if (i < NE_N) offs[i] = s[threadIdx.x] - v;   // exclusive within block
    if (threadIdx.x == 255) bsum[blockIdx.x] = s[255];
}

__global__ __launch_bounds__(512) void scan2_kernel(int* __restrict__ bsum, int nb)
{
    __shared__ int s[512];
    int t = threadIdx.x;
    int v = (t < nb) ? bsum[t] : 0;
    s[t] = v;
    __syncthreads();
    for (int off = 1; off < 512; off <<= 1) {
        int t_ = (t >= off) ? s[t - off] : 0;
        __syncthreads();
        s[t] += t_;
        __syncthreads();
    }
    if (t < nb) bsum[t] = s[t] - v;               // exclusive
}

__global__ __launch_bounds__(256) void scan3_kernel(
    int* __restrict__ offs, const int* __restrict__ bsum, int* __restrict__ cursor)
{
    int i = blockIdx.x * 256 + threadIdx.x;
    if (i < NE_N) {
        int o = offs[i] + bsum[blockIdx.x];
        offs[i] = o;
        cursor[i] = o;
    }
}

__global__ __launch_bounds__(256) void scatter_kernel(
    const int* __restrict__ dst, int* __restrict__ cursor, int* __restrict__ eidx)
{
    int t = blockIdx.x * 256 + threadIdx.x;
    if (t < NEDGE) {
        int pos = atomicAdd(&cursor[dst[t]], 1);
        eidx[pos] = t;
    }
}

// ---------------------------------------------------------------------------
// Fused encoder + MFMA projection.
// v2: Apack staged in LDS (shared by 4 waves) via async global_load_lds,
// double-buffered 8x64-col passes, counted s_waitcnt vmcnt(2) (never drain-0
// in the loop), one s_barrier per pass. Bias in LDS so the vmcnt queue per
// pass is exactly [4 staged loads][2 output stores].
// ---------------------------------------------------------------------------
__global__ __launch_bounds__(256, 4) void enc_proj_kernel(
    const float* __restrict__ featV, const float* __restrict__ WencV,
    const float* __restrict__ bencV, const float* __restrict__ gV,
    const float* __restrict__ betaV, const bf16_t* __restrict__ ApackV,
    const float* __restrict__ bprojV, unsigned short* __restrict__ outV,
    const float* __restrict__ featE, const float* __restrict__ WencE,
    const float* __restrict__ bencE, const float* __restrict__ gE,
    const float* __restrict__ betaE, const bf16_t* __restrict__ ApackE,
    const float* __restrict__ bprojE, unsigned short* __restrict__ outE,
    int nblk1, int M)
{
    __shared__ unsigned short Hs[64 * 136];                 // 17408 B
    __shared__ __align__(16) unsigned short Abuf[2][8192];  // 2 x 16 KB
    __shared__ __align__(16) float Bias[512];               // 2 KB

    int b = blockIdx.x;
    bool isV = b < nblk1;
    const float* feat  = isV ? featV  : featE;
    const float* Wenc  = isV ? WencV  : WencE;
    const float* benc  = isV ? bencV  : bencE;
    const float* gln   = isV ? gV     : gE;
    const float* beta  = isV ? betaV  : betaE;
    const bf16_t* Apack = isV ? ApackV : ApackE;
    const float* bproj = isV ? bprojV : bprojE;
    unsigned short* out = isV ? outV : outE;
    int row0 = (isV ? b : b - nblk1) * 64;

    int t = threadIdx.x;
    int l = t & 63;
    int w = t >> 6;
    int rbase = __builtin_amdgcn_readfirstlane(w * 16);  // scalar row base

    // ---- stage pass-0 A-tile (16 KB) + bias into LDS, async, before encoder
#pragma unroll
    for (int j = 0; j < 4; ++j) {
        int ksq = w * 4 + j;
        gload_lds16(Apack + ((size_t)(ksq * 512) + l) * 8, &Abuf[0][ksq * 512]);
    }
    if (t < 128)
        *(float4*)&Bias[t * 4] = *(const float4*)(bproj + t * 4);

    // ---- encoder: lane owns cols 2l, 2l+1 for the wave's 16 rows
    float wc0[16], wc1[16];
#pragma unroll
    for (int k = 0; k < 16; ++k) {
        float2 wv = *(const float2*)(Wenc + k * 128 + 2 * l);
        wc0[k] = wv.x;
        wc1[k] = wv.y;
    }
    float2 bv2 = *(const float2*)(benc + 2 * l);

#pragma unroll
    for (int i = 0; i < 16; ++i) {
        int grow = row0 + rbase + i;
        if (grow >= M) grow = M - 1;          // wave-uniform clamp
        const float* fr = feat + (size_t)grow * 16;
        float a0 = bv2.x, a1 = bv2.y;
#pragma unroll
        for (int k = 0; k < 16; ++k) {
            float f = fr[k];                  // scalar (wave-uniform) load
            a0 = fmaf(f, wc0[k], a0);
            a1 = fmaf(f, wc1[k], a1);
        }
        a0 = fmaxf(a0, 0.f);
        a1 = fmaxf(a1, 0.f);
        *(unsigned*)&Hs[(rbase + i) * 136 + 2 * l] = pk2(a0, a1);
    }

    // ---- LN stats, wave-local: lane -> (own row l>>2, quad l&3)
    float s = 0.f, s2 = 0.f;
    {
        int rr = rbase + (l >> 2);
        int q = l & 3;
#pragma unroll
        for (int j = 0; j < 4; ++j) {
            uint4 v = *(const uint4*)&Hs[rr * 136 + q * 32 + j * 8];
            float x;
            x = blo(v.x); s += x; s2 = fmaf(x, x, s2);
            x = bhi(v.x); s += x; s2 = fmaf(x, x, s2);
            x = blo(v.y); s += x; s2 = fmaf(x, x, s2);
            x = bhi(v.y); s += x; s2 = fmaf(x, x, s2);
            x = blo(v.z); s += x; s2 = fmaf(x, x, s2);
            x = bhi(v.z); s += x; s2 = fmaf(x, x, s2);
            x = blo(v.w); s += x; s2 = fmaf(x, x, s2);
            x = bhi(v.w); s += x; s2 = fmaf(x, x, s2);
        }
    }
    s  += __shfl_xor(s, 1, 64);  s  += __shfl_xor(s, 2, 64);
    s2 += __shfl_xor(s2, 1, 64); s2 += __shfl_xor(s2, 2, 64);
    float mu  = s * (1.f / 128.f);
    float var = s2 * (1.f / 128.f) - mu * mu;
    float inv = rsqrtf(var + LN_EPS);

    // ---- B-fragments with LN affine folded in (registers only)
    int kq = l >> 4;
    int ln = l & 15;
    float mu_r  = __shfl(mu,  ln * 4, 64);    // stats live at lane row*4
    float inv_r = __shfl(inv, ln * 4, 64);

    bf16x8 bfr[4];
#pragma unroll
    for (int ks = 0; ks < 4; ++ks) {
        int c0 = ks * 32 + kq * 8;
        uint4 v = *(const uint4*)&Hs[(rbase + ln) * 136 + c0];
        float4 g0 = *(const float4*)(gln + c0);
        float4 g1 = *(const float4*)(gln + c0 + 4);
        float4 b0 = *(const float4*)(beta + c0);
        float4 b1 = *(const float4*)(beta + c0 + 4);
        uint4 p;
        p.x = pk2(fmaf((blo(v.x) - mu_r) * inv_r, g0.x, b0.x),
                  fmaf((bhi(v.x) - mu_r) * inv_r, g0.y, b0.y));
        p.y = pk2(fmaf((blo(v.y) - mu_r) * inv_r, g0.z, b0.z),
                  fmaf((bhi(v.y) - mu_r) * inv_r, g0.w, b0.w));
        p.z = pk2(fmaf((blo(v.z) - mu_r) * inv_r, g1.x, b1.x),
                  fmaf((bhi(v.z) - mu_r) * inv_r, g1.y, b1.y));
        p.w = pk2(fmaf((blo(v.w) - mu_r) * inv_r, g1.z, b1.z),
                  fmaf((bhi(v.w) - mu_r) * inv_r, g1.w, b1.w));
        bfr[ks] = __builtin_bit_cast(bf16x8, p);
    }

    // ---- MFMA over 512 cols in 8 passes of 64; A-frags from LDS;
    //      next pass staged async under current pass's compute.
    unsigned short* stag = Hs + rbase * 136;
    int node = row0 + rbase + ln;
    bool wr = node < M;

#pragma unroll
    for (int p = 0; p < 8; ++p) {
        // wait own staged loads for pass p (and, p==0, bias/encoder LDS writes),
        // leave the previous pass's 2 output stores in flight.
        if (p == 0)
            asm volatile("s_waitcnt vmcnt(0) lgkmcnt(0)" ::: "memory");
        else
            asm volatile("s_waitcnt vmcnt(2)" ::: "memory");
        __builtin_amdgcn_s_barrier();   // all waves' tiles ready; prev buf free

        if (p < 7) {
#pragma unroll
            for (int j = 0; j < 4; ++j) {
                int ksq = w * 4 + j;
                gload_lds16(Apack + ((size_t)(ksq * 512 + (p + 1) * 64) + l) * 8,
                            &Abuf[(p + 1) & 1][ksq * 512]);
            }
            __builtin_amdgcn_sched_barrier(0);  // pin stage-issue before compute
        }

        const unsigned short* Ac = Abuf[p & 1];
#pragma unroll
        for (int mt = 0; mt < 4; ++mt) {
            bf16x8 a[4];
#pragma unroll
            for (int ks = 0; ks < 4; ++ks)
                a[ks] = *(const bf16x8*)&Ac[((ks * 4 + kq) * 64 + mt * 16 + ln) * 8];

            f32x4 acc = {0.f, 0.f, 0.f, 0.f};
#pragma unroll
            for (int ks = 0; ks < 4; ++ks)
                acc = __builtin_amdgcn_mfma_f32_16x16x32_bf16(a[ks], bfr[ks], acc, 0, 0, 0);

            int colp = p * 64 + mt * 16 + kq * 4;
            float4 bb = *(const float4*)&Bias[colp];
            ushort4 o;
            o.x = f2bfu(acc[0] + bb.x);
            o.y = f2bfu(acc[1] + bb.y);
            o.z = f2bfu(acc[2] + bb.z);
            o.w = f2bfu(acc[3] + bb.w);
            *(ushort4*)&stag[ln * 136 + mt * 16 + kq * 4] = o;
        }
        // 16 rows x 64 cols -> full 64B-line stores (2 insts/wave/pass)
#pragma unroll
        for (int i = 0; i < 2; ++i) {
            uint4 v = *(const uint4*)&stag[ln * 136 + i * 32 + kq * 8];
            if (wr)
                *(uint4*)(out + (size_t)node * 512 + p * 64 + i * 32 + kq * 8) = v;
        }
    }
}

// ---------------------------------------------------------------------------
// final GEMM (MFMA): C[M,128] = relu(A[M,128] @ Wp + bp), in place (A == C)
// ---------------------------------------------------------------------------
__global__ __launch_bounds__(256) void final_gemm_kernel(
    const float* __restrict__ A, const bf16_t* __restrict__ Ppack,
    const float* __restrict__ bp, float* __restrict__ C, int M)
{
    __shared__ unsigned short Hs[64 * 136];
    int t = threadIdx.x;
    int lane = t & 63;
    int w = t >> 6;
    int row0 = blockIdx.x * 64;

#pragma unroll
    for (int i = 0; i < 8; ++i) {
        int f4 = i * 256 + t;
        int r = f4 >> 5;
        int c4 = (f4 & 31) * 4;
        float4 v = make_float4(0.f, 0.f, 0.f, 0.f);
        if (row0 + r < M)
            v = ((const float4*)(A + (size_t)(row0 + r) * 128))[f4 & 31];
        ushort4 o;
        o.x = f2bfu(v.x); o.y = f2bfu(v.y); o.z = f2bfu(v.z); o.w = f2bfu(v.w);
        *(ushort4*)&Hs[r * 136 + c4] = o;
    }
    __syncthreads();

    int kq = lane >> 4;
    int ln = lane & 15;

    f32x4 acc[2][4];
#pragma unroll
    for (int mt = 0; mt < 2; ++mt)
#pragma unroll
        for (int nt = 0; nt < 4; ++nt) {
            f32x4 z = {0.f, 0.f, 0.f, 0.f};
            acc[mt][nt] = z;
        }

#pragma unroll
    for (int ks = 0; ks < 4; ++ks) {
        bf16x8 bfr[4];
#pragma unroll
        for (int nt = 0; nt < 4; ++nt) {
            const uint4* p = (const uint4*)&Hs[(nt * 16 + ln) * 136 + ks * 32 + kq * 8];
            bfr[nt] = __builtin_bit_cast(bf16x8, *p);
        }
        bf16x8 afr[2];
#pragma unroll
        for (int mt = 0; mt < 2; ++mt) {
            int colA = w * 32 + mt * 16 + ln;
            afr[mt] = *(const bf16x8*)(Ppack + ((size_t)(ks * 4 + kq) * 128 + colA) * 8);
        }
#pragma unroll
        for (int mt = 0; mt < 2; ++mt)
#pragma unroll
            for (int nt = 0; nt < 4; ++nt)
                acc[mt][nt] = __builtin_amdgcn_mfma_f32_16x16x32_bf16(
                    afr[mt], bfr[nt], acc[mt][nt], 0, 0, 0);
    }

#pragma unroll
    for (int mt = 0; mt < 2; ++mt) {
        int col = w * 32 + mt * 16 + kq * 4;
        float4 bb = *(const float4*)(bp + col);
#pragma unroll
        for (int nt = 0; nt < 4; ++nt) {
            int node = row0 + nt * 16 + ln;
            if (node < M) {
                float4 o;
                o.x = fmaxf(acc[mt][nt][0] + bb.x, 0.f);
                o.y = fmaxf(acc[mt][nt][1] + bb.y, 0.f);
                o.z = fmaxf(acc[mt][nt][2] + bb.z, 0.f);
                o.w = fmaxf(acc[mt][nt][3] + bb.w, 0.f);
                *(float4*)(C + (size_t)node * 128 + col) = o;
            }
        }
    }
}

// ---------------------------------------------------------------------------
// FUSED score + segment-softmax + aggregate (online softmax, no atomics).
// v2: gathers batched 4 edges at a time so load latencies overlap instead of
// serializing behind the online-softmax dependency chain.
// ---------------------------------------------------------------------------
__global__ __launch_bounds__(256) void softagg_kernel(
    const unsigned short* __restrict__ fs, const unsigned short* __restrict__ fdp,
    const float* __restrict__ attn, const int* __restrict__ src,
    const int* __restrict__ offs, const int* __restrict__ deg,
    const int* __restrict__ eidx, float* __restrict__ out)
{
    int d = blockIdx.x * 4 + (threadIdx.x >> 6);
    if (d >= NE_N) return;
    int l = threadIdx.x & 63;
    int r0 = offs[d];
    int n = deg[d];
    int o = l * 8;

    uint4 fv = *(const uint4*)(fdp + (size_t)d * 512 + o);
    float fdv[8] = { blo(fv.x), bhi(fv.x), blo(fv.y), bhi(fv.y),
                     blo(fv.z), bhi(fv.z), blo(fv.w), bhi(fv.w) };
    float4 w0 = *(const float4*)(attn + o);
    float4 w1 = *(const float4*)(attn + o + 4);
    float wv[8] = { w0.x, w0.y, w0.z, w0.w, w1.x, w1.y, w1.z, w1.w };

    float m = -1e30f, sm = 0.f;
    float acc[8];
#pragma unroll
    for (int j = 0; j < 8; ++j) acc[j] = 0.f;

    for (int base = 0; base < n; base += 64) {
        int cnt = min(n - base, 64);
        int sl = 0;
        if (l < cnt) sl = src[eidx[r0 + base + l]];
        for (int i0 = 0; i0 < cnt; i0 += 4) {
            // issue up to 4 independent row gathers (latency overlapped)
            uint4 av[4];
#pragma unroll
            for (int j = 0; j < 4; ++j) {
                int idx = (i0 + j < cnt) ? i0 + j : cnt - 1;  // wave-uniform
                int s = __shfl(sl, idx, 64);
                av[j] = *(const uint4*)(fs + (size_t)s * 512 + o);
            }
            int mcnt = min(4, cnt - i0);
#pragma unroll
            for (int j = 0; j < 4; ++j) {
                if (j < mcnt) {                               // wave-uniform
                    float fsv[8] = { blo(av[j].x), bhi(av[j].x),
                                     blo(av[j].y), bhi(av[j].y),
                                     blo(av[j].z), bhi(av[j].z),
                                     blo(av[j].w), bhi(av[j].w) };
                    float p = 0.f;
#pragma unroll
                    for (int jj = 0; jj < 8; ++jj)
                        p = fmaf(lrelu(fsv[jj] + fdv[jj]), wv[jj], p);
#pragma unroll
                    for (int mk = 1; mk < 16; mk <<= 1)
                        p += __shfl_xor(p, mk, 64);
                    float mn = fmaxf(m, p);
                    float c  = __expf(m - mn);
                    float aw = __expf(p - mn);
                    sm = sm * c + aw;
                    m = mn;
#pragma unroll
                    for (int jj = 0; jj < 8; ++jj)
                        acc[jj] = fmaf(aw, fsv[jj], acc[jj] * c);
                }
            }
        }
    }

    float inv = (n > 0) ? 0.25f / sm : 0.f;
#pragma unroll
    for (int j = 0; j < 8; ++j) {
        float v = acc[j] * inv;
        v += __shfl_xor(v, 16, 64);
        v += __shfl_xor(v, 32, 64);
        acc[j] = v;
    }
    if (l < 16) {
        float4 o0 = make_float4(acc[0], acc[1], acc[2], acc[3]);
        float4 o1 = make_float4(acc[4], acc[5], acc[6], acc[7]);
        *(float4*)(out + (size_t)d * 128 + l * 8) = o0;
        *(float4*)(out + (size_t)d * 128 + l * 8 + 4) = o1;
    }
}

// ---------------------------------------------------------------------------
extern "C" void kernel_launch(void* const* d_in, const int* in_sizes, int n_in,
                              void* d_out, int out_size, void* d_ws, size_t ws_size,
                              hipStream_t stream)
{
    const float* v_feat = (const float*)d_in[0];
    const float* e_feat = (const float*)d_in[1];
    const float* Wv     = (const float*)d_in[2];
    const float* bv     = (const float*)d_in[3];
    const float* gv     = (const float*)d_in[4];
    const float* betav  = (const float*)d_in[5];
    const float* We     = (const float*)d_in[6];
    const float* be     = (const float*)d_in[7];
    const float* ge     = (const float*)d_in[8];
    const float* betae  = (const float*)d_in[9];
    const float* Wsrc   = (const float*)d_in[10];
    const float* bsrc   = (const float*)d_in[11];
    const float* Wdst   = (const float*)d_in[12];
    const float* bdst   = (const float*)d_in[13];
    const float* attn   = (const float*)d_in[14];
    const float* Wp     = (const float*)d_in[15];
    const float* bp     = (const float*)d_in[16];
    const int*   src    = (const int*)d_in[17];
    const int*   dst    = (const int*)d_in[18];
    float* out = (float*)d_out;

    unsigned short* fs = (unsigned short*)d_ws;
    unsigned short* fd = fs + (size_t)NV * 512;
    int* deg    = (int*)(fd + (size_t)NE_N * 512);
    int* offs   = deg + NE_N;
    int* cursor = offs + NE_N;
    int* bsum   = cursor + NE_N;
    int* eidx   = bsum + 512;
    bf16_t* pS  = (bf16_t*)(eidx + NEDGE);
    bf16_t* pD  = pS + 65536;
    bf16_t* pP  = pD + 65536;

    const int NB_SCAN = (NE_N + 255) / 256;   // 391

    prep_kernel<<<72, 256, 0, stream>>>(Wsrc, Wdst, Wp, pS, pD, pP);

    // CSR build
    hipMemsetAsync(deg, 0, (size_t)NE_N * sizeof(int), stream);
    count_kernel<<<(NEDGE + 255) / 256, 256, 0, stream>>>(dst, deg);
    scan1_kernel<<<NB_SCAN, 256, 0, stream>>>(deg, offs, bsum);
    scan2_kernel<<<1, 512, 0, stream>>>(bsum, NB_SCAN);
    scan3_kernel<<<NB_SCAN, 256, 0, stream>>>(offs, bsum, cursor);
    scatter_kernel<<<(NEDGE + 255) / 256, 256, 0, stream>>>(dst, cursor, eidx);

    enc_proj_kernel<<<3126, 256, 0, stream>>>(
        v_feat, Wv, bv, gv, betav, pS, bsrc, fs,
        e_feat, We, be, ge, betae, pD, bdst, fd,
        1563, 100000);

    softagg_kernel<<<NE_N / 4, 256, 0, stream>>>(fs, fd, attn, src, offs, deg,
                                                 eidx, out);

    final_gemm_kernel<<<1563, 256, 0, stream>>>(out, pP, bp, out, NE_N);
}

// Round 2
// 297.682 us; speedup vs baseline: 1.1308x; 1.1308x over previous
//
#include <hip/hip_runtime.h>
#include <hip/hip_bf16.h>
#include <math.h>

#define NV 100000
#define NE_N 100000
#define NEDGE 250000
#define NPAD 100032          // 1563*64 — padded row count for fs/fd
#define NEG 0.2f
#define LN_EPS 1e-5f

typedef __bf16 bf16_t;
typedef __bf16 bf16x8 __attribute__((ext_vector_type(8)));
typedef float f32x4 __attribute__((ext_vector_type(4)));

__device__ inline unsigned short f2bfu(float f) {
    return __builtin_bit_cast(unsigned short, (__bf16)f);
}
__device__ inline float bfu2f(unsigned short u) {
    return (float)__builtin_bit_cast(__bf16, u);
}
__device__ inline float blo(unsigned w) { return __uint_as_float(w << 16); }
__device__ inline float bhi(unsigned w) { return __uint_as_float(w & 0xffff0000u); }
__device__ inline float lrelu(float x) { return x > 0.f ? x : NEG * x; }
__device__ inline unsigned pk2(float a, float b) {
    return (unsigned)f2bfu(a) | ((unsigned)f2bfu(b) << 16);
}

// async global->LDS, 16B per lane; LDS dest is wave-uniform base + lane*16,
// global source may be per-lane.
__device__ __forceinline__ void gload_lds16(const void* g, void* l) {
    __builtin_amdgcn_global_load_lds(
        (const __attribute__((address_space(1))) unsigned int*)g,
        (__attribute__((address_space(3))) unsigned int*)l,
        16, 0, 0);
}

// ---------------------------------------------------------------------------
// prep: pack W matrices into bf16 A-fragment order:
//   pack[((ksq)*N + col)*8 + j] = W[ksq*8 + j][col],  ksq = 0..15 (K=128)
// ---------------------------------------------------------------------------
__global__ __launch_bounds__(256) void prep_kernel(
    const float* __restrict__ Wsrc, const float* __restrict__ Wdst,
    const float* __restrict__ Wp, bf16_t* __restrict__ pS,
    bf16_t* __restrict__ pD, bf16_t* __restrict__ pP)
{
    int t = blockIdx.x * 256 + threadIdx.x;
    if (t < 8192) {
        int ksq = t >> 9, col = t & 511;
#pragma unroll
        for (int j = 0; j < 8; ++j)
            pS[(size_t)t * 8 + j] = (bf16_t)Wsrc[(ksq * 8 + j) * 512 + col];
    } else if (t < 16384) {
        int g = t - 8192;
        int ksq = g >> 9, col = g & 511;
#pragma unroll
        for (int j = 0; j < 8; ++j)
            pD[(size_t)g * 8 + j] = (bf16_t)Wdst[(ksq * 8 + j) * 512 + col];
    } else if (t < 18432) {
        int g = t - 16384;
        int ksq = g >> 7, col = g & 127;
#pragma unroll
        for (int j = 0; j < 8; ++j)
            pP[(size_t)g * 8 + j] = (bf16_t)Wp[(ksq * 8 + j) * 128 + col];
    }
}

// ---------------------------------------------------------------------------
// CSR build kernels
// ---------------------------------------------------------------------------
__global__ __launch_bounds__(256) void count_kernel(
    const int* __restrict__ dst, int* __restrict__ deg)
{
    int t = blockIdx.x * 256 + threadIdx.x;
    if (t < NEDGE) atomicAdd(&deg[dst[t]], 1);
}

__global__ __launch_bounds__(256) void scan1_kernel(
    const int* __restrict__ deg, int* __restrict__ offs, int* __restrict__ bsum)
{
    __shared__ int s[256];
    int i = blockIdx.x * 256 + threadIdx.x;
    int v = (i < NE_N) ? deg[i] : 0;
    s[threadIdx.x] = v;
    __syncthreads();
    for (int off = 1; off < 256; off <<= 1) {
        int t_ = (threadIdx.x >= off) ? s[threadIdx.x - off] : 0;
        __syncthreads();
        s[threadIdx.x] += t_;
        __syncthreads();
    }
    if (i < NE_N) offs[i] = s[threadIdx.x] - v;   // exclusive within block
    if (threadIdx.x == 255) bsum[blockIdx.x] = s[255];
}

__global__ __launch_bounds__(512) void scan2_kernel(int* __restrict__ bsum, int nb)
{
    __shared__ int s[512];
    int t = threadIdx.x;
    int v = (t < nb) ? bsum[t] : 0;
    s[t] = v;
    __syncthreads();
    for (int off = 1; off < 512; off <<= 1) {
        int t_ = (t >= off) ? s[t - off] : 0;
        __syncthreads();
        s[t] += t_;
        __syncthreads();
    }
    if (t < nb) bsum[t] = s[t] - v;               // exclusive
}

__global__ __launch_bounds__(256) void scan3_kernel(
    int* __restrict__ offs, const int* __restrict__ bsum, int* __restrict__ cursor)
{
    int i = blockIdx.x * 256 + threadIdx.x;
    if (i < NE_N) {
        int o = offs[i] + bsum[blockIdx.x];
        offs[i] = o;
        cursor[i] = o;
    }
}

__global__ __launch_bounds__(256) void scatter_kernel(
    const int* __restrict__ dst, int* __restrict__ cursor, int* __restrict__ eidx)
{
    int t = blockIdx.x * 256 + threadIdx.x;
    if (t < NEDGE) {
        int pos = atomicAdd(&cursor[dst[t]], 1);
        eidx[pos] = t;
    }
}

// ---------------------------------------------------------------------------
// Fused encoder + MFMA projection.
// v3: feat tile staged into LDS (reuses Abuf[1], dead until pass 1) via
// per-lane-source global_load_lds — kills the 16x serialized scalar-load
// chain that dominated the wave critical path. Output rows padded to NPAD
// so all stores are unconditional and the counted vmcnt(2) is exact for
// every wave.
// ---------------------------------------------------------------------------
__global__ __launch_bounds__(256, 4) void enc_proj_kernel(
    const float* __restrict__ featV, const float* __restrict__ WencV,
    const float* __restrict__ bencV, const float* __restrict__ gV,
    const float* __restrict__ betaV, const bf16_t* __restrict__ ApackV,
    const float* __restrict__ bprojV, unsigned short* __restrict__ outV,
    const float* __restrict__ featE, const float* __restrict__ WencE,
    const float* __restrict__ bencE, const float* __restrict__ gE,
    const float* __restrict__ betaE, const bf16_t* __restrict__ ApackE,
    const float* __restrict__ bprojE, unsigned short* __restrict__ outE,
    int nblk1, int M)
{
    __shared__ unsigned short Hs[64 * 136];                 // 17408 B
    __shared__ __align__(16) unsigned short Abuf[2][8192];  // 2 x 16 KB
    __shared__ __align__(16) float Bias[512];               // 2 KB

    int b = blockIdx.x;
    bool isV = b < nblk1;
    const float* feat  = isV ? featV  : featE;
    const float* Wenc  = isV ? WencV  : WencE;
    const float* benc  = isV ? bencV  : bencE;
    const float* gln   = isV ? gV     : gE;
    const float* beta  = isV ? betaV  : betaE;
    const bf16_t* Apack = isV ? ApackV : ApackE;
    const float* bproj = isV ? bprojV : bprojE;
    unsigned short* out = isV ? outV : outE;
    int row0 = (isV ? b : b - nblk1) * 64;

    int t = threadIdx.x;
    int l = t & 63;
    int w = t >> 6;
    int rbase = __builtin_amdgcn_readfirstlane(w * 16);  // scalar row base

    // ---- stage this wave's 16 feat rows (16 rows x 64 B = 1 KB) into
    //      Abuf[1] (dead until pass 1). Lane l: row rbase+(l>>2), 16 B chunk
    //      (l&3). Source rows clamped (tail blocks read row M-1, harmless).
    {
        int sr = row0 + rbase + (l >> 2);
        if (sr > M - 1) sr = M - 1;
        gload_lds16(feat + (size_t)sr * 16 + (l & 3) * 4, &Abuf[1][w * 512]);
    }

    // ---- stage pass-0 A-tile (16 KB) + bias into LDS, async
#pragma unroll
    for (int j = 0; j < 4; ++j) {
        int ksq = w * 4 + j;
        gload_lds16(Apack + ((size_t)(ksq * 512) + l) * 8, &Abuf[0][ksq * 512]);
    }
    if (t < 128)
        *(float4*)&Bias[t * 4] = *(const float4*)(bproj + t * 4);

    // ---- encoder weights to registers (overlap with staging)
    float wc0[16], wc1[16];
#pragma unroll
    for (int k = 0; k < 16; ++k) {
        float2 wv = *(const float2*)(Wenc + k * 128 + 2 * l);
        wc0[k] = wv.x;
        wc1[k] = wv.y;
    }
    float2 bv2 = *(const float2*)(benc + 2 * l);

    // drain everything issued above (feat+Apack in LDS, weights in regs)
    asm volatile("s_waitcnt vmcnt(0)" ::: "memory");

    // ---- encoder: lane owns cols 2l, 2l+1 for the wave's 16 rows;
    //      feat from LDS broadcast (conflict-free, pipelined)
    const float* Fs = (const float*)&Abuf[1][0];
#pragma unroll
    for (int i = 0; i < 16; ++i) {
        const float* fr = Fs + (rbase + i) * 16;
        float4 f0 = *(const float4*)(fr);
        float4 f1 = *(const float4*)(fr + 4);
        float4 f2 = *(const float4*)(fr + 8);
        float4 f3 = *(const float4*)(fr + 12);
        float a0 = bv2.x, a1 = bv2.y;
        a0 = fmaf(f0.x, wc0[0], a0);  a1 = fmaf(f0.x, wc1[0], a1);
        a0 = fmaf(f0.y, wc0[1], a0);  a1 = fmaf(f0.y, wc1[1], a1);
        a0 = fmaf(f0.z, wc0[2], a0);  a1 = fmaf(f0.z, wc1[2], a1);
        a0 = fmaf(f0.w, wc0[3], a0);  a1 = fmaf(f0.w, wc1[3], a1);
        a0 = fmaf(f1.x, wc0[4], a0);  a1 = fmaf(f1.x, wc1[4], a1);
        a0 = fmaf(f1.y, wc0[5], a0);  a1 = fmaf(f1.y, wc1[5], a1);
        a0 = fmaf(f1.z, wc0[6], a0);  a1 = fmaf(f1.z, wc1[6], a1);
        a0 = fmaf(f1.w, wc0[7], a0);  a1 = fmaf(f1.w, wc1[7], a1);
        a0 = fmaf(f2.x, wc0[8], a0);  a1 = fmaf(f2.x, wc1[8], a1);
        a0 = fmaf(f2.y, wc0[9], a0);  a1 = fmaf(f2.y, wc1[9], a1);
        a0 = fmaf(f2.z, wc0[10], a0); a1 = fmaf(f2.z, wc1[10], a1);
        a0 = fmaf(f2.w, wc0[11], a0); a1 = fmaf(f2.w, wc1[11], a1);
        a0 = fmaf(f3.x, wc0[12], a0); a1 = fmaf(f3.x, wc1[12], a1);
        a0 = fmaf(f3.y, wc0[13], a0); a1 = fmaf(f3.y, wc1[13], a1);
        a0 = fmaf(f3.z, wc0[14], a0); a1 = fmaf(f3.z, wc1[14], a1);
        a0 = fmaf(f3.w, wc0[15], a0); a1 = fmaf(f3.w, wc1[15], a1);
        a0 = fmaxf(a0, 0.f);
        a1 = fmaxf(a1, 0.f);
        *(unsigned*)&Hs[(rbase + i) * 136 + 2 * l] = pk2(a0, a1);
    }

    // ---- LN stats, wave-local: lane -> (own row l>>2, quad l&3)
    float s = 0.f, s2 = 0.f;
    {
        int rr = rbase + (l >> 2);
        int q = l & 3;
#pragma unroll
        for (int j = 0; j < 4; ++j) {
            uint4 v = *(const uint4*)&Hs[rr * 136 + q * 32 + j * 8];
            float x;
            x = blo(v.x); s += x; s2 = fmaf(x, x, s2);
            x = bhi(v.x); s += x; s2 = fmaf(x, x, s2);
            x = blo(v.y); s += x; s2 = fmaf(x, x, s2);
            x = bhi(v.y); s += x; s2 = fmaf(x, x, s2);
            x = blo(v.z); s += x; s2 = fmaf(x, x, s2);
            x = bhi(v.z); s += x; s2 = fmaf(x, x, s2);
            x = blo(v.w); s += x; s2 = fmaf(x, x, s2);
            x = bhi(v.w); s += x; s2 = fmaf(x, x, s2);
        }
    }
    s  += __shfl_xor(s, 1, 64);  s  += __shfl_xor(s, 2, 64);
    s2 += __shfl_xor(s2, 1, 64); s2 += __shfl_xor(s2, 2, 64);
    float mu  = s * (1.f / 128.f);
    float var = s2 * (1.f / 128.f) - mu * mu;
    float inv = rsqrtf(var + LN_EPS);

    // ---- B-fragments with LN affine folded in (registers only)
    int kq = l >> 4;
    int ln = l & 15;
    float mu_r  = __shfl(mu,  ln * 4, 64);    // stats live at lane row*4
    float inv_r = __shfl(inv, ln * 4, 64);

    bf16x8 bfr[4];
#pragma unroll
    for (int ks = 0; ks < 4; ++ks) {
        int c0 = ks * 32 + kq * 8;
        uint4 v = *(const uint4*)&Hs[(rbase + ln) * 136 + c0];
        float4 g0 = *(const float4*)(gln + c0);
        float4 g1 = *(const float4*)(gln + c0 + 4);
        float4 b0 = *(const float4*)(beta + c0);
        float4 b1 = *(const float4*)(beta + c0 + 4);
        uint4 p;
        p.x = pk2(fmaf((blo(v.x) - mu_r) * inv_r, g0.x, b0.x),
                  fmaf((bhi(v.x) - mu_r) * inv_r, g0.y, b0.y));
        p.y = pk2(fmaf((blo(v.y) - mu_r) * inv_r, g0.z, b0.z),
                  fmaf((bhi(v.y) - mu_r) * inv_r, g0.w, b0.w));
        p.z = pk2(fmaf((blo(v.z) - mu_r) * inv_r, g1.x, b1.x),
                  fmaf((bhi(v.z) - mu_r) * inv_r, g1.y, b1.y));
        p.w = pk2(fmaf((blo(v.w) - mu_r) * inv_r, g1.z, b1.z),
                  fmaf((bhi(v.w) - mu_r) * inv_r, g1.w, b1.w));
        bfr[ks] = __builtin_bit_cast(bf16x8, p);
    }

    // ---- MFMA over 512 cols in 8 passes of 64; A-frags from LDS;
    //      next pass staged async under current pass's compute.
    unsigned short* stag = Hs + rbase * 136;
    int node = row0 + rbase + ln;        // always < NPAD rows — no guard

#pragma unroll
    for (int p = 0; p < 8; ++p) {
        // p==0: vmcnt already 0 (pre-encoder drain); only Hs/bias ds ops
        // pending. p>0: wait own 4 stage loads, leave prev 2 stores in flight.
        if (p == 0)
            asm volatile("s_waitcnt lgkmcnt(0)" ::: "memory");
        else
            asm volatile("s_waitcnt vmcnt(2)" ::: "memory");
        __builtin_amdgcn_s_barrier();   // all waves' tiles ready; prev buf free

        if (p < 7) {
#pragma unroll
            for (int j = 0; j < 4; ++j) {
                int ksq = w * 4 + j;
                gload_lds16(Apack + ((size_t)(ksq * 512 + (p + 1) * 64) + l) * 8,
                            &Abuf[(p + 1) & 1][ksq * 512]);
            }
            __builtin_amdgcn_sched_barrier(0);  // pin stage-issue before compute
        }

        const unsigned short* Ac = Abuf[p & 1];
#pragma unroll
        for (int mt = 0; mt < 4; ++mt) {
            bf16x8 a[4];
#pragma unroll
            for (int ks = 0; ks < 4; ++ks)
                a[ks] = *(const bf16x8*)&Ac[((ks * 4 + kq) * 64 + mt * 16 + ln) * 8];

            f32x4 acc = {0.f, 0.f, 0.f, 0.f};
#pragma unroll
            for (int ks = 0; ks < 4; ++ks)
                acc = __builtin_amdgcn_mfma_f32_16x16x32_bf16(a[ks], bfr[ks], acc, 0, 0, 0);

            int colp = p * 64 + mt * 16 + kq * 4;
            float4 bb = *(const float4*)&Bias[colp];
            ushort4 o;
            o.x = f2bfu(acc[0] + bb.x);
            o.y = f2bfu(acc[1] + bb.y);
            o.z = f2bfu(acc[2] + bb.z);
            o.w = f2bfu(acc[3] + bb.w);
            *(ushort4*)&stag[ln * 136 + mt * 16 + kq * 4] = o;
        }
        // 16 rows x 64 cols -> full 64B-line stores (2 insts/wave/pass),
        // unconditional (rows padded to NPAD) so vmcnt count is exact.
#pragma unroll
        for (int i = 0; i < 2; ++i) {
            uint4 v = *(const uint4*)&stag[ln * 136 + i * 32 + kq * 8];
            *(uint4*)(out + (size_t)node * 512 + p * 64 + i * 32 + kq * 8) = v;
        }
    }
}

// ---------------------------------------------------------------------------
// final GEMM (MFMA): C[M,128] = relu(A[M,128] @ Wp + bp), in place (A == C)
// ---------------------------------------------------------------------------
__global__ __launch_bounds__(256) void final_gemm_kernel(
    const float* __restrict__ A, const bf16_t* __restrict__ Ppack,
    const float* __restrict__ bp, float* __restrict__ C, int M)
{
    __shared__ unsigned short Hs[64 * 136];
    int t = threadIdx.x;
    int lane = t & 63;
    int w = t >> 6;
    int row0 = blockIdx.x * 64;

#pragma unroll
    for (int i = 0; i < 8; ++i) {
        int f4 = i * 256 + t;
        int r = f4 >> 5;
        int c4 = (f4 & 31) * 4;
        float4 v = make_float4(0.f, 0.f, 0.f, 0.f);
        if (row0 + r < M)
            v = ((const float4*)(A + (size_t)(row0 + r) * 128))[f4 & 31];
        ushort4 o;
        o.x = f2bfu(v.x); o.y = f2bfu(v.y); o.z = f2bfu(v.z); o.w = f2bfu(v.w);
        *(ushort4*)&Hs[r * 136 + c4] = o;
    }
    __syncthreads();

    int kq = lane >> 4;
    int ln = lane & 15;

    f32x4 acc[2][4];
#pragma unroll
    for (int mt = 0; mt < 2; ++mt)
#pragma unroll
        for (int nt = 0; nt < 4; ++nt) {
            f32x4 z = {0.f, 0.f, 0.f, 0.f};
            acc[mt][nt] = z;
        }

#pragma unroll
    for (int ks = 0; ks < 4; ++ks) {
        bf16x8 bfr[4];
#pragma unroll
        for (int nt = 0; nt < 4; ++nt) {
            const uint4* p = (const uint4*)&Hs[(nt * 16 + ln) * 136 + ks * 32 + kq * 8];
            bfr[nt] = __builtin_bit_cast(bf16x8, *p);
        }
        bf16x8 afr[2];
#pragma unroll
        for (int mt = 0; mt < 2; ++mt) {
            int colA = w * 32 + mt * 16 + ln;
            afr[mt] = *(const bf16x8*)(Ppack + ((size_t)(ks * 4 + kq) * 128 + colA) * 8);
        }
#pragma unroll
        for (int mt = 0; mt < 2; ++mt)
#pragma unroll
            for (int nt = 0; nt < 4; ++nt)
                acc[mt][nt] = __builtin_amdgcn_mfma_f32_16x16x32_bf16(
                    afr[mt], bfr[nt], acc[mt][nt], 0, 0, 0);
    }

#pragma unroll
    for (int mt = 0; mt < 2; ++mt) {
        int col = w * 32 + mt * 16 + kq * 4;
        float4 bb = *(const float4*)(bp + col);
#pragma unroll
        for (int nt = 0; nt < 4; ++nt) {
            int node = row0 + nt * 16 + ln;
            if (node < M) {
                float4 o;
                o.x = fmaxf(acc[mt][nt][0] + bb.x, 0.f);
                o.y = fmaxf(acc[mt][nt][1] + bb.y, 0.f);
                o.z = fmaxf(acc[mt][nt][2] + bb.z, 0.f);
                o.w = fmaxf(acc[mt][nt][3] + bb.w, 0.f);
                *(float4*)(C + (size_t)node * 128 + col) = o;
            }
        }
    }
}

// ---------------------------------------------------------------------------
// FUSED score + segment-softmax + aggregate (online softmax, no atomics).
// (round-0 form — the batched-gather variant regressed ~19 µs; compiler
// already overlaps the independent row gathers.)
// ---------------------------------------------------------------------------
__global__ __launch_bounds__(256) void softagg_kernel(
    const unsigned short* __restrict__ fs, const unsigned short* __restrict__ fdp,
    const float* __restrict__ attn, const int* __restrict__ src,
    const int* __restrict__ offs, const int* __restrict__ deg,
    const int* __restrict__ eidx, float* __restrict__ out)
{
    int d = blockIdx.x * 4 + (threadIdx.x >> 6);
    if (d >= NE_N) return;
    int l = threadIdx.x & 63;
    int r0 = offs[d];
    int n = deg[d];
    int o = l * 8;

    uint4 fv = *(const uint4*)(fdp + (size_t)d * 512 + o);
    float fdv[8] = { blo(fv.x), bhi(fv.x), blo(fv.y), bhi(fv.y),
                     blo(fv.z), bhi(fv.z), blo(fv.w), bhi(fv.w) };
    float4 w0 = *(const float4*)(attn + o);
    float4 w1 = *(const float4*)(attn + o + 4);
    float wv[8] = { w0.x, w0.y, w0.z, w0.w, w1.x, w1.y, w1.z, w1.w };

    float m = -1e30f, sm = 0.f;
    float acc[8];
#pragma unroll
    for (int j = 0; j < 8; ++j) acc[j] = 0.f;

    for (int base = 0; base < n; base += 64) {
        int cnt = min(n - base, 64);
        int sl = 0;
        if (l < cnt) sl = src[eidx[r0 + base + l]];
        for (int i = 0; i < cnt; ++i) {
            int s = __shfl(sl, i, 64);
            uint4 a = *(const uint4*)(fs + (size_t)s * 512 + o);
            float fsv[8] = { blo(a.x), bhi(a.x), blo(a.y), bhi(a.y),
                             blo(a.z), bhi(a.z), blo(a.w), bhi(a.w) };
            float p = 0.f;
#pragma unroll
            for (int j = 0; j < 8; ++j)
                p = fmaf(lrelu(fsv[j] + fdv[j]), wv[j], p);
#pragma unroll
            for (int mk = 1; mk < 16; mk <<= 1)
                p += __shfl_xor(p, mk, 64);
            float mn = fmaxf(m, p);
            float c  = __expf(m - mn);
            float av = __expf(p - mn);
            sm = sm * c + av;
            m = mn;
#pragma unroll
            for (int j = 0; j < 8; ++j)
                acc[j] = fmaf(av, fsv[j], acc[j] * c);
        }
    }

    float inv = (n > 0) ? 0.25f / sm : 0.f;
#pragma unroll
    for (int j = 0; j < 8; ++j) {
        float v = acc[j] * inv;
        v += __shfl_xor(v, 16, 64);
        v += __shfl_xor(v, 32, 64);
        acc[j] = v;
    }
    if (l < 16) {
        float4 o0 = make_float4(acc[0], acc[1], acc[2], acc[3]);
        float4 o1 = make_float4(acc[4], acc[5], acc[6], acc[7]);
        *(float4*)(out + (size_t)d * 128 + l * 8) = o0;
        *(float4*)(out + (size_t)d * 128 + l * 8 + 4) = o1;
    }
}

// ---------------------------------------------------------------------------
extern "C" void kernel_launch(void* const* d_in, const int* in_sizes, int n_in,
                              void* d_out, int out_size, void* d_ws, size_t ws_size,
                              hipStream_t stream)
{
    const float* v_feat = (const float*)d_in[0];
    const float* e_feat = (const float*)d_in[1];
    const float* Wv     = (const float*)d_in[2];
    const float* bv     = (const float*)d_in[3];
    const float* gv     = (const float*)d_in[4];
    const float* betav  = (const float*)d_in[5];
    const float* We     = (const float*)d_in[6];
    const float* be     = (const float*)d_in[7];
    const float* ge     = (const float*)d_in[8];
    const float* betae  = (const float*)d_in[9];
    const float* Wsrc   = (const float*)d_in[10];
    const float* bsrc   = (const float*)d_in[11];
    const float* Wdst   = (const float*)d_in[12];
    const float* bdst   = (const float*)d_in[13];
    const float* attn   = (const float*)d_in[14];
    const float* Wp     = (const float*)d_in[15];
    const float* bp     = (const float*)d_in[16];
    const int*   src    = (const int*)d_in[17];
    const int*   dst    = (const int*)d_in[18];
    float* out = (float*)d_out;

    unsigned short* fs = (unsigned short*)d_ws;
    unsigned short* fd = fs + (size_t)NPAD * 512;
    int* deg    = (int*)(fd + (size_t)NPAD * 512);
    int* offs   = deg + NE_N;
    int* cursor = offs + NE_N;
    int* bsum   = cursor + NE_N;
    int* eidx   = bsum + 512;
    bf16_t* pS  = (bf16_t*)(eidx + NEDGE);
    bf16_t* pD  = pS + 65536;
    bf16_t* pP  = pD + 65536;

    const int NB_SCAN = (NE_N + 255) / 256;   // 391

    prep_kernel<<<72, 256, 0, stream>>>(Wsrc, Wdst, Wp, pS, pD, pP);

    // CSR build
    hipMemsetAsync(deg, 0, (size_t)NE_N * sizeof(int), stream);
    count_kernel<<<(NEDGE + 255) / 256, 256, 0, stream>>>(dst, deg);
    scan1_kernel<<<NB_SCAN, 256, 0, stream>>>(deg, offs, bsum);
    scan2_kernel<<<1, 512, 0, stream>>>(bsum, NB_SCAN);
    scan3_kernel<<<NB_SCAN, 256, 0, stream>>>(offs, bsum, cursor);
    scatter_kernel<<<(NEDGE + 255) / 256, 256, 0, stream>>>(dst, cursor, eidx);

    enc_proj_kernel<<<3126, 256, 0, stream>>>(
        v_feat, Wv, bv, gv, betav, pS, bsrc, fs,
        e_feat, We, be, ge, betae, pD, bdst, fd,
        1563, 100000);

    softagg_kernel<<<NE_N / 4, 256, 0, stream>>>(fs, fd, attn, src, offs, deg,
                                                 eidx, out);

    final_gemm_kernel<<<1563, 256, 0, stream>>>(out, pP, bp, out, NE_N);
}

// Round 3
// 291.469 us; speedup vs baseline: 1.1549x; 1.0213x over previous
//
#include <hip/hip_runtime.h>
#include <hip/hip_bf16.h>
#include <math.h>

#define NV 100000
#define NE_N 100000
#define NEDGE 250000
#define NPAD 100096          // 782*128 — padded row count for fs/fd
#define NEG 0.2f
#define LN_EPS 1e-5f

typedef __bf16 bf16_t;
typedef __bf16 bf16x8 __attribute__((ext_vector_type(8)));
typedef float f32x4 __attribute__((ext_vector_type(4)));
typedef float f32x2 __attribute__((ext_vector_type(2)));

__device__ inline unsigned short f2bfu(float f) {
    return __builtin_bit_cast(unsigned short, (__bf16)f);
}
__device__ inline float blo(unsigned w) { return __uint_as_float(w << 16); }
__device__ inline float bhi(unsigned w) { return __uint_as_float(w & 0xffff0000u); }
__device__ inline float lrelu(float x) { return x > 0.f ? x : NEG * x; }
__device__ inline unsigned pk2(float a, float b) {
    return (unsigned)f2bfu(a) | ((unsigned)f2bfu(b) << 16);
}

// async global->LDS, 16B per lane; LDS dest is wave-uniform base + lane*16,
// global source may be per-lane.
__device__ __forceinline__ void gload_lds16(const void* g, void* l) {
    __builtin_amdgcn_global_load_lds(
        (const __attribute__((address_space(1))) unsigned int*)g,
        (__attribute__((address_space(3))) unsigned int*)l,
        16, 0, 0);
}

// ---------------------------------------------------------------------------
// prep: pack W matrices into bf16 A-fragment order; also zeroes deg[]
// (folds the hipMemsetAsync launch away).
//   pack[((ksq)*N + col)*8 + j] = W[ksq*8 + j][col],  ksq = 0..15 (K=128)
// ---------------------------------------------------------------------------
__global__ __launch_bounds__(256) void prep_kernel(
    const float* __restrict__ Wsrc, const float* __restrict__ Wdst,
    const float* __restrict__ Wp, bf16_t* __restrict__ pS,
    bf16_t* __restrict__ pD, bf16_t* __restrict__ pP,
    int* __restrict__ deg)
{
    int t = blockIdx.x * 256 + threadIdx.x;
    if (t < 8192) {
        int ksq = t >> 9, col = t & 511;
#pragma unroll
        for (int j = 0; j < 8; ++j)
            pS[(size_t)t * 8 + j] = (bf16_t)Wsrc[(ksq * 8 + j) * 512 + col];
    } else if (t < 16384) {
        int g = t - 8192;
        int ksq = g >> 9, col = g & 511;
#pragma unroll
        for (int j = 0; j < 8; ++j)
            pD[(size_t)g * 8 + j] = (bf16_t)Wdst[(ksq * 8 + j) * 512 + col];
    } else if (t < 18432) {
        int g = t - 16384;
        int ksq = g >> 7, col = g & 127;
#pragma unroll
        for (int j = 0; j < 8; ++j)
            pP[(size_t)g * 8 + j] = (bf16_t)Wp[(ksq * 8 + j) * 128 + col];
    } else {
        int z = t - 18432;
        if (z < NE_N) deg[z] = 0;
    }
}

// ---------------------------------------------------------------------------
// CSR build kernels
// ---------------------------------------------------------------------------
__global__ __launch_bounds__(256) void count_kernel(
    const int* __restrict__ dst, int* __restrict__ deg)
{
    int t = blockIdx.x * 256 + threadIdx.x;
    if (t < NEDGE) atomicAdd(&deg[dst[t]], 1);
}

__global__ __launch_bounds__(256) void scan1_kernel(
    const int* __restrict__ deg, int* __restrict__ offs, int* __restrict__ bsum)
{
    __shared__ int s[256];
    int i = blockIdx.x * 256 + threadIdx.x;
    int v = (i < NE_N) ? deg[i] : 0;
    s[threadIdx.x] = v;
    __syncthreads();
    for (int off = 1; off < 256; off <<= 1) {
        int t_ = (threadIdx.x >= off) ? s[threadIdx.x - off] : 0;
        __syncthreads();
        s[threadIdx.x] += t_;
        __syncthreads();
    }
    if (i < NE_N) offs[i] = s[threadIdx.x] - v;   // exclusive within block
    if (threadIdx.x == 255) bsum[blockIdx.x] = s[255];
}

__global__ __launch_bounds__(512) void scan2_kernel(int* __restrict__ bsum, int nb)
{
    __shared__ int s[512];
    int t = threadIdx.x;
    int v = (t < nb) ? bsum[t] : 0;
    s[t] = v;
    __syncthreads();
    for (int off = 1; off < 512; off <<= 1) {
        int t_ = (t >= off) ? s[t - off] : 0;
        __syncthreads();
        s[t] += t_;
        __syncthreads();
    }
    if (t < nb) bsum[t] = s[t] - v;               // exclusive
}

__global__ __launch_bounds__(256) void scan3_kernel(
    int* __restrict__ offs, const int* __restrict__ bsum, int* __restrict__ cursor)
{
    int i = blockIdx.x * 256 + threadIdx.x;
    if (i < NE_N) {
        int o = offs[i] + bsum[blockIdx.x];
        offs[i] = o;
        cursor[i] = o;
    }
}

__global__ __launch_bounds__(256) void scatter_kernel(
    const int* __restrict__ dst, int* __restrict__ cursor, int* __restrict__ eidx)
{
    int t = blockIdx.x * 256 + threadIdx.x;
    if (t < NEDGE) {
        int pos = atomicAdd(&cursor[dst[t]], 1);
        eidx[pos] = t;
    }
}

// ---------------------------------------------------------------------------
// Fused encoder + MFMA projection.
// v4: 512-thread blocks (8 waves, 128 rows) — same Abuf amortized over 2x
// rows -> LDS 69632 B -> 2 blocks/CU = 16 waves/CU (~2x TLP vs v3).
// Encoder uses f32x2 packed FMA (v_pk_fma_f32) halving its VALU issue.
// Counted vmcnt(2) discipline unchanged: per wave per pass exactly
// [2 stage loads][2 output stores].
// ---------------------------------------------------------------------------
__global__ __launch_bounds__(512, 4) void enc_proj_kernel(
    const float* __restrict__ featV, const float* __restrict__ WencV,
    const float* __restrict__ bencV, const float* __restrict__ gV,
    const float* __restrict__ betaV, const bf16_t* __restrict__ ApackV,
    const float* __restrict__ bprojV, unsigned short* __restrict__ outV,
    const float* __restrict__ featE, const float* __restrict__ WencE,
    const float* __restrict__ bencE, const float* __restrict__ gE,
    const float* __restrict__ betaE, const bf16_t* __restrict__ ApackE,
    const float* __restrict__ bprojE, unsigned short* __restrict__ outE,
    int nblk1, int M)
{
    __shared__ unsigned short Hs[128 * 136];                // 34816 B
    __shared__ __align__(16) unsigned short Abuf[2][8192];  // 2 x 16 KB
    __shared__ __align__(16) float Bias[512];               // 2 KB

    int b = blockIdx.x;
    bool isV = b < nblk1;
    const float* feat  = isV ? featV  : featE;
    const float* Wenc  = isV ? WencV  : WencE;
    const float* benc  = isV ? bencV  : bencE;
    const float* gln   = isV ? gV     : gE;
    const float* beta  = isV ? betaV  : betaE;
    const bf16_t* Apack = isV ? ApackV : ApackE;
    const float* bproj = isV ? bprojV : bprojE;
    unsigned short* out = isV ? outV : outE;
    int row0 = (isV ? b : b - nblk1) * 128;

    int t = threadIdx.x;
    int l = t & 63;
    int w = t >> 6;                                       // 0..7
    int rbase = __builtin_amdgcn_readfirstlane(w * 16);   // scalar row base

    // ---- stage this wave's 16 feat rows (1 KB) into Abuf[1] (dead until
    //      pass 1). Lane l: row rbase+(l>>2), 16 B chunk (l&3).
    {
        int sr = row0 + rbase + (l >> 2);
        if (sr > M - 1) sr = M - 1;
        gload_lds16(feat + (size_t)sr * 16 + (l & 3) * 4, &Abuf[1][w * 512]);
    }

    // ---- stage pass-0 A-tile (16 KB over 8 waves -> 2 loads/wave) + bias
#pragma unroll
    for (int j = 0; j < 2; ++j) {
        int ksq = w * 2 + j;
        gload_lds16(Apack + ((size_t)(ksq * 512) + l) * 8, &Abuf[0][ksq * 512]);
    }
    if (t < 128)
        *(float4*)&Bias[t * 4] = *(const float4*)(bproj + t * 4);

    // ---- encoder weights to registers (overlap with staging)
    f32x2 wc2[16];
#pragma unroll
    for (int k = 0; k < 16; ++k) {
        float2 wv = *(const float2*)(Wenc + k * 128 + 2 * l);
        wc2[k][0] = wv.x;
        wc2[k][1] = wv.y;
    }
    float2 bv2 = *(const float2*)(benc + 2 * l);

    // drain everything issued above (feat+Apack in LDS, weights in regs)
    asm volatile("s_waitcnt vmcnt(0)" ::: "memory");

    // ---- encoder: lane owns cols 2l, 2l+1 for the wave's 16 rows;
    //      feat from LDS broadcast; packed f32x2 FMA (v_pk_fma_f32)
    const float* Fs = (const float*)&Abuf[1][0];
#pragma unroll
    for (int i = 0; i < 16; ++i) {
        const float* fr = Fs + (rbase + i) * 16;
        float4 f0 = *(const float4*)(fr);
        float4 f1 = *(const float4*)(fr + 4);
        float4 f2 = *(const float4*)(fr + 8);
        float4 f3 = *(const float4*)(fr + 12);
        f32x2 a = {bv2.x, bv2.y};
        a = __builtin_elementwise_fma((f32x2)f0.x, wc2[0],  a);
        a = __builtin_elementwise_fma((f32x2)f0.y, wc2[1],  a);
        a = __builtin_elementwise_fma((f32x2)f0.z, wc2[2],  a);
        a = __builtin_elementwise_fma((f32x2)f0.w, wc2[3],  a);
        a = __builtin_elementwise_fma((f32x2)f1.x, wc2[4],  a);
        a = __builtin_elementwise_fma((f32x2)f1.y, wc2[5],  a);
        a = __builtin_elementwise_fma((f32x2)f1.z, wc2[6],  a);
        a = __builtin_elementwise_fma((f32x2)f1.w, wc2[7],  a);
        a = __builtin_elementwise_fma((f32x2)f2.x, wc2[8],  a);
        a = __builtin_elementwise_fma((f32x2)f2.y, wc2[9],  a);
        a = __builtin_elementwise_fma((f32x2)f2.z, wc2[10], a);
        a = __builtin_elementwise_fma((f32x2)f2.w, wc2[11], a);
        a = __builtin_elementwise_fma((f32x2)f3.x, wc2[12], a);
        a = __builtin_elementwise_fma((f32x2)f3.y, wc2[13], a);
        a = __builtin_elementwise_fma((f32x2)f3.z, wc2[14], a);
        a = __builtin_elementwise_fma((f32x2)f3.w, wc2[15], a);
        float a0 = fmaxf(a[0], 0.f);
        float a1 = fmaxf(a[1], 0.f);
        *(unsigned*)&Hs[(rbase + i) * 136 + 2 * l] = pk2(a0, a1);
    }

    // ---- LN stats, wave-local: lane -> (own row l>>2, quad l&3)
    float s = 0.f, s2 = 0.f;
    {
        int rr = rbase + (l >> 2);
        int q = l & 3;
#pragma unroll
        for (int j = 0; j < 4; ++j) {
            uint4 v = *(const uint4*)&Hs[rr * 136 + q * 32 + j * 8];
            float x;
            x = blo(v.x); s += x; s2 = fmaf(x, x, s2);
            x = bhi(v.x); s += x; s2 = fmaf(x, x, s2);
            x = blo(v.y); s += x; s2 = fmaf(x, x, s2);
            x = bhi(v.y); s += x; s2 = fmaf(x, x, s2);
            x = blo(v.z); s += x; s2 = fmaf(x, x, s2);
            x = bhi(v.z); s += x; s2 = fmaf(x, x, s2);
            x = blo(v.w); s += x; s2 = fmaf(x, x, s2);
            x = bhi(v.w); s += x; s2 = fmaf(x, x, s2);
        }
    }
    s  += __shfl_xor(s, 1, 64);  s  += __shfl_xor(s, 2, 64);
    s2 += __shfl_xor(s2, 1, 64); s2 += __shfl_xor(s2, 2, 64);
    float mu  = s * (1.f / 128.f);
    float var = s2 * (1.f / 128.f) - mu * mu;
    float inv = rsqrtf(var + LN_EPS);

    // ---- B-fragments with LN affine folded in (registers only)
    int kq = l >> 4;
    int ln = l & 15;
    float mu_r  = __shfl(mu,  ln * 4, 64);    // stats live at lane row*4
    float inv_r = __shfl(inv, ln * 4, 64);

    bf16x8 bfr[4];
#pragma unroll
    for (int ks = 0; ks < 4; ++ks) {
        int c0 = ks * 32 + kq * 8;
        uint4 v = *(const uint4*)&Hs[(rbase + ln) * 136 + c0];
        float4 g0 = *(const float4*)(gln + c0);
        float4 g1 = *(const float4*)(gln + c0 + 4);
        float4 b0 = *(const float4*)(beta + c0);
        float4 b1 = *(const float4*)(beta + c0 + 4);
        uint4 p;
        p.x = pk2(fmaf((blo(v.x) - mu_r) * inv_r, g0.x, b0.x),
                  fmaf((bhi(v.x) - mu_r) * inv_r, g0.y, b0.y));
        p.y = pk2(fmaf((blo(v.y) - mu_r) * inv_r, g0.z, b0.z),
                  fmaf((bhi(v.y) - mu_r) * inv_r, g0.w, b0.w));
        p.z = pk2(fmaf((blo(v.z) - mu_r) * inv_r, g1.x, b1.x),
                  fmaf((bhi(v.z) - mu_r) * inv_r, g1.y, b1.y));
        p.w = pk2(fmaf((blo(v.w) - mu_r) * inv_r, g1.z, b1.z),
                  fmaf((bhi(v.w) - mu_r) * inv_r, g1.w, b1.w));
        bfr[ks] = __builtin_bit_cast(bf16x8, p);
    }

    // ---- MFMA over 512 cols in 8 passes of 64; A-frags from LDS;
    //      next pass staged async under current pass's compute.
    unsigned short* stag = Hs + rbase * 136;
    int node = row0 + rbase + ln;        // always < NPAD rows — no guard

#pragma unroll
    for (int p = 0; p < 8; ++p) {
        // p==0: vmcnt already 0 (pre-encoder drain); only Hs/bias ds ops
        // pending. p>0: wait own 2 stage loads, leave prev 2 stores in flight.
        if (p == 0)
            asm volatile("s_waitcnt lgkmcnt(0)" ::: "memory");
        else
            asm volatile("s_waitcnt vmcnt(2)" ::: "memory");
        __builtin_amdgcn_s_barrier();   // all waves' tiles ready; prev buf free

        if (p < 7) {
#pragma unroll
            for (int j = 0; j < 2; ++j) {
                int ksq = w * 2 + j;
                gload_lds16(Apack + ((size_t)(ksq * 512 + (p + 1) * 64) + l) * 8,
                            &Abuf[(p + 1) & 1][ksq * 512]);
            }
            __builtin_amdgcn_sched_barrier(0);  // pin stage-issue before compute
        }

        const unsigned short* Ac = Abuf[p & 1];
#pragma unroll
        for (int mt = 0; mt < 4; ++mt) {
            bf16x8 a[4];
#pragma unroll
            for (int ks = 0; ks < 4; ++ks)
                a[ks] = *(const bf16x8*)&Ac[((ks * 4 + kq) * 64 + mt * 16 + ln) * 8];

            f32x4 acc = {0.f, 0.f, 0.f, 0.f};
#pragma unroll
            for (int ks = 0; ks < 4; ++ks)
                acc = __builtin_amdgcn_mfma_f32_16x16x32_bf16(a[ks], bfr[ks], acc, 0, 0, 0);

            int colp = p * 64 + mt * 16 + kq * 4;
            float4 bb = *(const float4*)&Bias[colp];
            ushort4 o;
            o.x = f2bfu(acc[0] + bb.x);
            o.y = f2bfu(acc[1] + bb.y);
            o.z = f2bfu(acc[2] + bb.z);
            o.w = f2bfu(acc[3] + bb.w);
            *(ushort4*)&stag[ln * 136 + mt * 16 + kq * 4] = o;
        }
        // 16 rows x 64 cols -> full 64B-line stores (2 insts/wave/pass),
        // unconditional (rows padded to NPAD) so vmcnt count is exact.
#pragma unroll
        for (int i = 0; i < 2; ++i) {
            uint4 v = *(const uint4*)&stag[ln * 136 + i * 32 + kq * 8];
            *(uint4*)(out + (size_t)node * 512 + p * 64 + i * 32 + kq * 8) = v;
        }
    }
}

// ---------------------------------------------------------------------------
// final GEMM (MFMA): C[M,128] = relu(A @ Wp + bp). A is bf16 (Abf) when the
// workspace fits the staging buffer, else f32 in-place (A == C fallback).
// ---------------------------------------------------------------------------
__global__ __launch_bounds__(256) void final_gemm_kernel(
    const float* __restrict__ A, const unsigned short* __restrict__ Abf,
    const bf16_t* __restrict__ Ppack, const float* __restrict__ bp,
    float* __restrict__ C, int M)
{
    __shared__ unsigned short Hs[64 * 136];
    int t = threadIdx.x;
    int lane = t & 63;
    int w = t >> 6;
    int row0 = blockIdx.x * 64;

    if (Abf) {
#pragma unroll
        for (int i = 0; i < 4; ++i) {
            int idx = i * 256 + t;       // 1024 16B-chunks: 64 rows x 16
            int r = idx >> 4;
            int c = (idx & 15) * 8;
            uint4 v = make_uint4(0, 0, 0, 0);
            if (row0 + r < M)
                v = *(const uint4*)(Abf + (size_t)(row0 + r) * 128 + c);
            *(uint4*)&Hs[r * 136 + c] = v;
        }
    } else {
#pragma unroll
        for (int i = 0; i < 8; ++i) {
            int f4 = i * 256 + t;
            int r = f4 >> 5;
            int c4 = (f4 & 31) * 4;
            float4 v = make_float4(0.f, 0.f, 0.f, 0.f);
            if (row0 + r < M)
                v = ((const float4*)(A + (size_t)(row0 + r) * 128))[f4 & 31];
            ushort4 o;
            o.x = f2bfu(v.x); o.y = f2bfu(v.y); o.z = f2bfu(v.z); o.w = f2bfu(v.w);
            *(ushort4*)&Hs[r * 136 + c4] = o;
        }
    }
    __syncthreads();

    int kq = lane >> 4;
    int ln = lane & 15;

    f32x4 acc[2][4];
#pragma unroll
    for (int mt = 0; mt < 2; ++mt)
#pragma unroll
        for (int nt = 0; nt < 4; ++nt) {
            f32x4 z = {0.f, 0.f, 0.f, 0.f};
            acc[mt][nt] = z;
        }

#pragma unroll
    for (int ks = 0; ks < 4; ++ks) {
        bf16x8 bfr[4];
#pragma unroll
        for (int nt = 0; nt < 4; ++nt) {
            const uint4* p = (const uint4*)&Hs[(nt * 16 + ln) * 136 + ks * 32 + kq * 8];
            bfr[nt] = __builtin_bit_cast(bf16x8, *p);
        }
        bf16x8 afr[2];
#pragma unroll
        for (int mt = 0; mt < 2; ++mt) {
            int colA = w * 32 + mt * 16 + ln;
            afr[mt] = *(const bf16x8*)(Ppack + ((size_t)(ks * 4 + kq) * 128 + colA) * 8);
        }
#pragma unroll
        for (int mt = 0; mt < 2; ++mt)
#pragma unroll
            for (int nt = 0; nt < 4; ++nt)
                acc[mt][nt] = __builtin_amdgcn_mfma_f32_16x16x32_bf16(
                    afr[mt], bfr[nt], acc[mt][nt], 0, 0, 0);
    }

#pragma unroll
    for (int mt = 0; mt < 2; ++mt) {
        int col = w * 32 + mt * 16 + kq * 4;
        float4 bb = *(const float4*)(bp + col);
#pragma unroll
        for (int nt = 0; nt < 4; ++nt) {
            int node = row0 + nt * 16 + ln;
            if (node < M) {
                float4 o;
                o.x = fmaxf(acc[mt][nt][0] + bb.x, 0.f);
                o.y = fmaxf(acc[mt][nt][1] + bb.y, 0.f);
                o.z = fmaxf(acc[mt][nt][2] + bb.z, 0.f);
                o.w = fmaxf(acc[mt][nt][3] + bb.w, 0.f);
                *(float4*)(C + (size_t)node * 128 + col) = o;
            }
        }
    }
}

// ---------------------------------------------------------------------------
// FUSED score + segment-softmax + aggregate (online softmax, no atomics).
// Writes edge_out as bf16 (eo != null) — bit-identical to the old path,
// which rounded to bf16 at final_gemm staging anyway — halving the
// intermediate traffic. f32 fallback writes to outf.
// ---------------------------------------------------------------------------
__global__ __launch_bounds__(256) void softagg_kernel(
    const unsigned short* __restrict__ fs, const unsigned short* __restrict__ fdp,
    const float* __restrict__ attn, const int* __restrict__ src,
    const int* __restrict__ offs, const int* __restrict__ deg,
    const int* __restrict__ eidx, float* __restrict__ outf,
    unsigned short* __restrict__ eo)
{
    int d = blockIdx.x * 4 + (threadIdx.x >> 6);
    if (d >= NE_N) return;
    int l = threadIdx.x & 63;
    int r0 = offs[d];
    int n = deg[d];
    int o = l * 8;

    uint4 fv = *(const uint4*)(fdp + (size_t)d * 512 + o);
    float fdv[8] = { blo(fv.x), bhi(fv.x), blo(fv.y), bhi(fv.y),
                     blo(fv.z), bhi(fv.z), blo(fv.w), bhi(fv.w) };
    float4 w0 = *(const float4*)(attn + o);
    float4 w1 = *(const float4*)(attn + o + 4);
    float wv[8] = { w0.x, w0.y, w0.z, w0.w, w1.x, w1.y, w1.z, w1.w };

    float m = -1e30f, sm = 0.f;
    float acc[8];
#pragma unroll
    for (int j = 0; j < 8; ++j) acc[j] = 0.f;

    for (int base = 0; base < n; base += 64) {
        int cnt = min(n - base, 64);
        int sl = 0;
        if (l < cnt) sl = src[eidx[r0 + base + l]];
        for (int i = 0; i < cnt; ++i) {
            int s = __shfl(sl, i, 64);
            uint4 a = *(const uint4*)(fs + (size_t)s * 512 + o);
            float fsv[8] = { blo(a.x), bhi(a.x), blo(a.y), bhi(a.y),
                             blo(a.z), bhi(a.z), blo(a.w), bhi(a.w) };
            float p = 0.f;
#pragma unroll
            for (int j = 0; j < 8; ++j)
                p = fmaf(lrelu(fsv[j] + fdv[j]), wv[j], p);
#pragma unroll
            for (int mk = 1; mk < 16; mk <<= 1)
                p += __shfl_xor(p, mk, 64);
            float mn = fmaxf(m, p);
            float c  = __expf(m - mn);
            float av = __expf(p - mn);
            sm = sm * c + av;
            m = mn;
#pragma unroll
            for (int j = 0; j < 8; ++j)
                acc[j] = fmaf(av, fsv[j], acc[j] * c);
        }
    }

    float inv = (n > 0) ? 0.25f / sm : 0.f;
#pragma unroll
    for (int j = 0; j < 8; ++j) {
        float v = acc[j] * inv;
        v += __shfl_xor(v, 16, 64);
        v += __shfl_xor(v, 32, 64);
        acc[j] = v;
    }
    if (l < 16) {
        if (eo) {
            uint4 pk;
            pk.x = pk2(acc[0], acc[1]);
            pk.y = pk2(acc[2], acc[3]);
            pk.z = pk2(acc[4], acc[5]);
            pk.w = pk2(acc[6], acc[7]);
            *(uint4*)(eo + (size_t)d * 128 + l * 8) = pk;
        } else {
            float4 o0 = make_float4(acc[0], acc[1], acc[2], acc[3]);
            float4 o1 = make_float4(acc[4], acc[5], acc[6], acc[7]);
            *(float4*)(outf + (size_t)d * 128 + l * 8) = o0;
            *(float4*)(outf + (size_t)d * 128 + l * 8 + 4) = o1;
        }
    }
}

// ---------------------------------------------------------------------------
extern "C" void kernel_launch(void* const* d_in, const int* in_sizes, int n_in,
                              void* d_out, int out_size, void* d_ws, size_t ws_size,
                              hipStream_t stream)
{
    const float* v_feat = (const float*)d_in[0];
    const float* e_feat = (const float*)d_in[1];
    const float* Wv     = (const float*)d_in[2];
    const float* bv     = (const float*)d_in[3];
    const float* gv     = (const float*)d_in[4];
    const float* betav  = (const float*)d_in[5];
    const float* We     = (const float*)d_in[6];
    const float* be     = (const float*)d_in[7];
    const float* ge     = (const float*)d_in[8];
    const float* betae  = (const float*)d_in[9];
    const float* Wsrc   = (const float*)d_in[10];
    const float* bsrc   = (const float*)d_in[11];
    const float* Wdst   = (const float*)d_in[12];
    const float* bdst   = (const float*)d_in[13];
    const float* attn   = (const float*)d_in[14];
    const float* Wp     = (const float*)d_in[15];
    const float* bp     = (const float*)d_in[16];
    const int*   src    = (const int*)d_in[17];
    const int*   dst    = (const int*)d_in[18];
    float* out = (float*)d_out;

    unsigned short* fs = (unsigned short*)d_ws;
    unsigned short* fd = fs + (size_t)NPAD * 512;
    int* deg    = (int*)(fd + (size_t)NPAD * 512);
    int* offs   = deg + NE_N;
    int* cursor = offs + NE_N;
    int* bsum   = cursor + NE_N;
    int* eidx   = bsum + 512;
    bf16_t* pS  = (bf16_t*)(eidx + NEDGE);
    bf16_t* pD  = pS + 65536;
    bf16_t* pP  = pD + 65536;
    unsigned short* eo = (unsigned short*)(pP + 16384);

    size_t need = (size_t)((char*)(eo + (size_t)NE_N * 128) - (char*)d_ws);
    if (ws_size < need) eo = nullptr;   // f32 fallback path

    const int NB_SCAN = (NE_N + 255) / 256;   // 391

    // prep packs + zero deg (463 blocks: 72 pack + 391 zero)
    prep_kernel<<<463, 256, 0, stream>>>(Wsrc, Wdst, Wp, pS, pD, pP, deg);

    // CSR build
    count_kernel<<<(NEDGE + 255) / 256, 256, 0, stream>>>(dst, deg);
    scan1_kernel<<<NB_SCAN, 256, 0, stream>>>(deg, offs, bsum);
    scan2_kernel<<<1, 512, 0, stream>>>(bsum, NB_SCAN);
    scan3_kernel<<<NB_SCAN, 256, 0, stream>>>(offs, bsum, cursor);
    scatter_kernel<<<(NEDGE + 255) / 256, 256, 0, stream>>>(dst, cursor, eidx);

    enc_proj_kernel<<<1564, 512, 0, stream>>>(
        v_feat, Wv, bv, gv, betav, pS, bsrc, fs,
        e_feat, We, be, ge, betae, pD, bdst, fd,
        782, 100000);

    softagg_kernel<<<NE_N / 4, 256, 0, stream>>>(fs, fd, attn, src, offs, deg,
                                                 eidx, out, eo);

    final_gemm_kernel<<<1563, 256, 0, stream>>>(out, eo, pP, bp, out, NE_N);
}

// Round 4
// 287.012 us; speedup vs baseline: 1.1728x; 1.0155x over previous
//
#include <hip/hip_runtime.h>
#include <hip/hip_bf16.h>
#include <math.h>

#define NV 100000
#define NE_N 100000
#define NEDGE 250000
#define NPAD 100032          // 1563*64 — padded row count for fs/fd
#define NEG 0.2f
#define LN_EPS 1e-5f

typedef __bf16 bf16_t;
typedef __bf16 bf16x8 __attribute__((ext_vector_type(8)));
typedef float f32x4 __attribute__((ext_vector_type(4)));
typedef float f32x2 __attribute__((ext_vector_type(2)));

__device__ inline unsigned short f2bfu(float f) {
    return __builtin_bit_cast(unsigned short, (__bf16)f);
}
__device__ inline float blo(unsigned w) { return __uint_as_float(w << 16); }
__device__ inline float bhi(unsigned w) { return __uint_as_float(w & 0xffff0000u); }
__device__ inline float lrelu(float x) { return x > 0.f ? x : NEG * x; }
__device__ inline unsigned pk2(float a, float b) {
    return (unsigned)f2bfu(a) | ((unsigned)f2bfu(b) << 16);
}

// async global->LDS, 16B per lane; LDS dest is wave-uniform base + lane*16,
// global source may be per-lane.
__device__ __forceinline__ void gload_lds16(const void* g, void* l) {
    __builtin_amdgcn_global_load_lds(
        (const __attribute__((address_space(1))) unsigned int*)g,
        (__attribute__((address_space(3))) unsigned int*)l,
        16, 0, 0);
}

// ---------------------------------------------------------------------------
// prep: pack W matrices into bf16 A-fragment order; also zeroes deg[]
// (folds the hipMemsetAsync launch away).
//   pack[((ksq)*N + col)*8 + j] = W[ksq*8 + j][col],  ksq = 0..15 (K=128)
// ---------------------------------------------------------------------------
__global__ __launch_bounds__(256) void prep_kernel(
    const float* __restrict__ Wsrc, const float* __restrict__ Wdst,
    const float* __restrict__ Wp, bf16_t* __restrict__ pS,
    bf16_t* __restrict__ pD, bf16_t* __restrict__ pP,
    int* __restrict__ deg)
{
    int t = blockIdx.x * 256 + threadIdx.x;
    if (t < 8192) {
        int ksq = t >> 9, col = t & 511;
#pragma unroll
        for (int j = 0; j < 8; ++j)
            pS[(size_t)t * 8 + j] = (bf16_t)Wsrc[(ksq * 8 + j) * 512 + col];
    } else if (t < 16384) {
        int g = t - 8192;
        int ksq = g >> 9, col = g & 511;
#pragma unroll
        for (int j = 0; j < 8; ++j)
            pD[(size_t)g * 8 + j] = (bf16_t)Wdst[(ksq * 8 + j) * 512 + col];
    } else if (t < 18432) {
        int g = t - 16384;
        int ksq = g >> 7, col = g & 127;
#pragma unroll
        for (int j = 0; j < 8; ++j)
            pP[(size_t)g * 8 + j] = (bf16_t)Wp[(ksq * 8 + j) * 128 + col];
    } else {
        int z = t - 18432;
        if (z < NE_N) deg[z] = 0;
    }
}

// ---------------------------------------------------------------------------
// CSR build kernels
// ---------------------------------------------------------------------------
__global__ __launch_bounds__(256) void count_kernel(
    const int* __restrict__ dst, int* __restrict__ deg)
{
    int t = blockIdx.x * 256 + threadIdx.x;
    if (t < NEDGE) atomicAdd(&deg[dst[t]], 1);
}

__global__ __launch_bounds__(256) void scan1_kernel(
    const int* __restrict__ deg, int* __restrict__ offs, int* __restrict__ bsum)
{
    __shared__ int s[256];
    int i = blockIdx.x * 256 + threadIdx.x;
    int v = (i < NE_N) ? deg[i] : 0;
    s[threadIdx.x] = v;
    __syncthreads();
    for (int off = 1; off < 256; off <<= 1) {
        int t_ = (threadIdx.x >= off) ? s[threadIdx.x - off] : 0;
        __syncthreads();
        s[threadIdx.x] += t_;
        __syncthreads();
    }
    if (i < NE_N) offs[i] = s[threadIdx.x] - v;   // exclusive within block
    if (threadIdx.x == 255) bsum[blockIdx.x] = s[255];
}

__global__ __launch_bounds__(512) void scan2_kernel(int* __restrict__ bsum, int nb)
{
    __shared__ int s[512];
    int t = threadIdx.x;
    int v = (t < nb) ? bsum[t] : 0;
    s[t] = v;
    __syncthreads();
    for (int off = 1; off < 512; off <<= 1) {
        int t_ = (t >= off) ? s[t - off] : 0;
        __syncthreads();
        s[t] += t_;
        __syncthreads();
    }
    if (t < nb) bsum[t] = s[t] - v;               // exclusive
}

// scan3: finalize offsets + cursor + fused (offs,deg) pairs for softagg
__global__ __launch_bounds__(256) void scan3_kernel(
    int* __restrict__ offs, const int* __restrict__ bsum,
    int* __restrict__ cursor, const int* __restrict__ deg,
    int2* __restrict__ od)
{
    int i = blockIdx.x * 256 + threadIdx.x;
    if (i < NE_N) {
        int o = offs[i] + bsum[blockIdx.x];
        offs[i] = o;
        cursor[i] = o;
        od[i] = make_int2(o, deg[i]);
    }
}

// scatter: store the SRC NODE ID directly (kills the eidx->src indirection
// in softagg's dependent-load chain)
__global__ __launch_bounds__(256) void scatter_kernel(
    const int* __restrict__ dst, const int* __restrict__ src,
    int* __restrict__ cursor, int* __restrict__ srcs)
{
    int t = blockIdx.x * 256 + threadIdx.x;
    if (t < NEDGE) {
        int pos = atomicAdd(&cursor[dst[t]], 1);
        srcs[pos] = src[t];
    }
}

// ---------------------------------------------------------------------------
// Fused encoder + MFMA projection.
// v5: 256-thr structure of v3 (measured 84.5 µs; the 512-thr variant
// regressed — 8-wave barrier lockstep killed phase diversity) + the f32x2
// packed-FMA encoder from v4 (halves encoder VALU issue).
// Counted vmcnt(2) per pass: [4 stage loads][2 output stores].
// ---------------------------------------------------------------------------
__global__ __launch_bounds__(256, 4) void enc_proj_kernel(
    const float* __restrict__ featV, const float* __restrict__ WencV,
    const float* __restrict__ bencV, const float* __restrict__ gV,
    const float* __restrict__ betaV, const bf16_t* __restrict__ ApackV,
    const float* __restrict__ bprojV, unsigned short* __restrict__ outV,
    const float* __restrict__ featE, const float* __restrict__ WencE,
    const float* __restrict__ bencE, const float* __restrict__ gE,
    const float* __restrict__ betaE, const bf16_t* __restrict__ ApackE,
    const float* __restrict__ bprojE, unsigned short* __restrict__ outE,
    int nblk1, int M)
{
    __shared__ unsigned short Hs[64 * 136];                 // 17408 B
    __shared__ __align__(16) unsigned short Abuf[2][8192];  // 2 x 16 KB
    __shared__ __align__(16) float Bias[512];               // 2 KB

    int b = blockIdx.x;
    bool isV = b < nblk1;
    const float* feat  = isV ? featV  : featE;
    const float* Wenc  = isV ? WencV  : WencE;
    const float* benc  = isV ? bencV  : bencE;
    const float* gln   = isV ? gV     : gE;
    const float* beta  = isV ? betaV  : betaE;
    const bf16_t* Apack = isV ? ApackV : ApackE;
    const float* bproj = isV ? bprojV : bprojE;
    unsigned short* out = isV ? outV : outE;
    int row0 = (isV ? b : b - nblk1) * 64;

    int t = threadIdx.x;
    int l = t & 63;
    int w = t >> 6;                                       // 0..3
    int rbase = __builtin_amdgcn_readfirstlane(w * 16);   // scalar row base

    // ---- stage this wave's 16 feat rows (1 KB) into Abuf[1] (dead until
    //      pass 1). Lane l: row rbase+(l>>2), 16 B chunk (l&3).
    {
        int sr = row0 + rbase + (l >> 2);
        if (sr > M - 1) sr = M - 1;
        gload_lds16(feat + (size_t)sr * 16 + (l & 3) * 4, &Abuf[1][w * 512]);
    }

    // ---- stage pass-0 A-tile (16 KB, 4 loads/wave) + bias
#pragma unroll
    for (int j = 0; j < 4; ++j) {
        int ksq = w * 4 + j;
        gload_lds16(Apack + ((size_t)(ksq * 512) + l) * 8, &Abuf[0][ksq * 512]);
    }
    if (t < 128)
        *(float4*)&Bias[t * 4] = *(const float4*)(bproj + t * 4);

    // ---- encoder weights to registers (overlap with staging)
    f32x2 wc2[16];
#pragma unroll
    for (int k = 0; k < 16; ++k) {
        float2 wv = *(const float2*)(Wenc + k * 128 + 2 * l);
        wc2[k][0] = wv.x;
        wc2[k][1] = wv.y;
    }
    float2 bv2 = *(const float2*)(benc + 2 * l);

    // drain everything issued above (feat+Apack in LDS, weights in regs)
    asm volatile("s_waitcnt vmcnt(0)" ::: "memory");

    // ---- encoder: lane owns cols 2l, 2l+1 for the wave's 16 rows;
    //      feat from LDS broadcast; packed f32x2 FMA (v_pk_fma_f32)
    const float* Fs = (const float*)&Abuf[1][0];
#pragma unroll
    for (int i = 0; i < 16; ++i) {
        const float* fr = Fs + (rbase + i) * 16;
        float4 f0 = *(const float4*)(fr);
        float4 f1 = *(const float4*)(fr + 4);
        float4 f2 = *(const float4*)(fr + 8);
        float4 f3 = *(const float4*)(fr + 12);
        f32x2 a = {bv2.x, bv2.y};
        a = __builtin_elementwise_fma((f32x2)f0.x, wc2[0],  a);
        a = __builtin_elementwise_fma((f32x2)f0.y, wc2[1],  a);
        a = __builtin_elementwise_fma((f32x2)f0.z, wc2[2],  a);
        a = __builtin_elementwise_fma((f32x2)f0.w, wc2[3],  a);
        a = __builtin_elementwise_fma((f32x2)f1.x, wc2[4],  a);
        a = __builtin_elementwise_fma((f32x2)f1.y, wc2[5],  a);
        a = __builtin_elementwise_fma((f32x2)f1.z, wc2[6],  a);
        a = __builtin_elementwise_fma((f32x2)f1.w, wc2[7],  a);
        a = __builtin_elementwise_fma((f32x2)f2.x, wc2[8],  a);
        a = __builtin_elementwise_fma((f32x2)f2.y, wc2[9],  a);
        a = __builtin_elementwise_fma((f32x2)f2.z, wc2[10], a);
        a = __builtin_elementwise_fma((f32x2)f2.w, wc2[11], a);
        a = __builtin_elementwise_fma((f32x2)f3.x, wc2[12], a);
        a = __builtin_elementwise_fma((f32x2)f3.y, wc2[13], a);
        a = __builtin_elementwise_fma((f32x2)f3.z, wc2[14], a);
        a = __builtin_elementwise_fma((f32x2)f3.w, wc2[15], a);
        float a0 = fmaxf(a[0], 0.f);
        float a1 = fmaxf(a[1], 0.f);
        *(unsigned*)&Hs[(rbase + i) * 136 + 2 * l] = pk2(a0, a1);
    }

    // ---- LN stats, wave-local: lane -> (own row l>>2, quad l&3)
    float s = 0.f, s2 = 0.f;
    {
        int rr = rbase + (l >> 2);
        int q = l & 3;
#pragma unroll
        for (int j = 0; j < 4; ++j) {
            uint4 v = *(const uint4*)&Hs[rr * 136 + q * 32 + j * 8];
            float x;
            x = blo(v.x); s += x; s2 = fmaf(x, x, s2);
            x = bhi(v.x); s += x; s2 = fmaf(x, x, s2);
            x = blo(v.y); s += x; s2 = fmaf(x, x, s2);
            x = bhi(v.y); s += x; s2 = fmaf(x, x, s2);
            x = blo(v.z); s += x; s2 = fmaf(x, x, s2);
            x = bhi(v.z); s += x; s2 = fmaf(x, x, s2);
            x = blo(v.w); s += x; s2 = fmaf(x, x, s2);
            x = bhi(v.w); s += x; s2 = fmaf(x, x, s2);
        }
    }
    s  += __shfl_xor(s, 1, 64);  s  += __shfl_xor(s, 2, 64);
    s2 += __shfl_xor(s2, 1, 64); s2 += __shfl_xor(s2, 2, 64);
    float mu  = s * (1.f / 128.f);
    float var = s2 * (1.f / 128.f) - mu * mu;
    float inv = rsqrtf(var + LN_EPS);

    // ---- B-fragments with LN affine folded in (registers only)
    int kq = l >> 4;
    int ln = l & 15;
    float mu_r  = __shfl(mu,  ln * 4, 64);    // stats live at lane row*4
    float inv_r = __shfl(inv, ln * 4, 64);

    bf16x8 bfr[4];
#pragma unroll
    for (int ks = 0; ks < 4; ++ks) {
        int c0 = ks * 32 + kq * 8;
        uint4 v = *(const uint4*)&Hs[(rbase + ln) * 136 + c0];
        float4 g0 = *(const float4*)(gln + c0);
        float4 g1 = *(const float4*)(gln + c0 + 4);
        float4 b0 = *(const float4*)(beta + c0);
        float4 b1 = *(const float4*)(beta + c0 + 4);
        uint4 p;
        p.x = pk2(fmaf((blo(v.x) - mu_r) * inv_r, g0.x, b0.x),
                  fmaf((bhi(v.x) - mu_r) * inv_r, g0.y, b0.y));
        p.y = pk2(fmaf((blo(v.y) - mu_r) * inv_r, g0.z, b0.z),
                  fmaf((bhi(v.y) - mu_r) * inv_r, g0.w, b0.w));
        p.z = pk2(fmaf((blo(v.z) - mu_r) * inv_r, g1.x, b1.x),
                  fmaf((bhi(v.z) - mu_r) * inv_r, g1.y, b1.y));
        p.w = pk2(fmaf((blo(v.w) - mu_r) * inv_r, g1.z, b1.z),
                  fmaf((bhi(v.w) - mu_r) * inv_r, g1.w, b1.w));
        bfr[ks] = __builtin_bit_cast(bf16x8, p);
    }

    // ---- MFMA over 512 cols in 8 passes of 64; A-frags from LDS;
    //      next pass staged async under current pass's compute.
    unsigned short* stag = Hs + rbase * 136;
    int node = row0 + rbase + ln;        // always < NPAD rows — no guard

#pragma unroll
    for (int p = 0; p < 8; ++p) {
        // p==0: vmcnt already 0 (pre-encoder drain); only Hs/bias ds ops
        // pending. p>0: wait own 4 stage loads, leave prev 2 stores in flight.
        if (p == 0)
            asm volatile("s_waitcnt lgkmcnt(0)" ::: "memory");
        else
            asm volatile("s_waitcnt vmcnt(2)" ::: "memory");
        __builtin_amdgcn_s_barrier();   // all waves' tiles ready; prev buf free

        if (p < 7) {
#pragma unroll
            for (int j = 0; j < 4; ++j) {
                int ksq = w * 4 + j;
                gload_lds16(Apack + ((size_t)(ksq * 512 + (p + 1) * 64) + l) * 8,
                            &Abuf[(p + 1) & 1][ksq * 512]);
            }
            __builtin_amdgcn_sched_barrier(0);  // pin stage-issue before compute
        }

        const unsigned short* Ac = Abuf[p & 1];
#pragma unroll
        for (int mt = 0; mt < 4; ++mt) {
            bf16x8 a[4];
#pragma unroll
            for (int ks = 0; ks < 4; ++ks)
                a[ks] = *(const bf16x8*)&Ac[((ks * 4 + kq) * 64 + mt * 16 + ln) * 8];

            f32x4 acc = {0.f, 0.f, 0.f, 0.f};
#pragma unroll
            for (int ks = 0; ks < 4; ++ks)
                acc = __builtin_amdgcn_mfma_f32_16x16x32_bf16(a[ks], bfr[ks], acc, 0, 0, 0);

            int colp = p * 64 + mt * 16 + kq * 4;
            float4 bb = *(const float4*)&Bias[colp];
            ushort4 o;
            o.x = f2bfu(acc[0] + bb.x);
            o.y = f2bfu(acc[1] + bb.y);
            o.z = f2bfu(acc[2] + bb.z);
            o.w = f2bfu(acc[3] + bb.w);
            *(ushort4*)&stag[ln * 136 + mt * 16 + kq * 4] = o;
        }
        // 16 rows x 64 cols -> full 64B-line stores (2 insts/wave/pass),
        // unconditional (rows padded to NPAD) so vmcnt count is exact.
#pragma unroll
        for (int i = 0; i < 2; ++i) {
            uint4 v = *(const uint4*)&stag[ln * 136 + i * 32 + kq * 8];
            *(uint4*)(out + (size_t)node * 512 + p * 64 + i * 32 + kq * 8) = v;
        }
    }
}

// ---------------------------------------------------------------------------
// final GEMM (MFMA): C[M,128] = relu(A @ Wp + bp). A is bf16 (Abf) when the
// workspace fits the staging buffer, else f32 in-place (A == C fallback).
// ---------------------------------------------------------------------------
__global__ __launch_bounds__(256) void final_gemm_kernel(
    const float* __restrict__ A, const unsigned short* __restrict__ Abf,
    const bf16_t* __restrict__ Ppack, const float* __restrict__ bp,
    float* __restrict__ C, int M)
{
    __shared__ unsigned short Hs[64 * 136];
    int t = threadIdx.x;
    int lane = t & 63;
    int w = t >> 6;
    int row0 = blockIdx.x * 64;

    if (Abf) {
#pragma unroll
        for (int i = 0; i < 4; ++i) {
            int idx = i * 256 + t;       // 1024 16B-chunks: 64 rows x 16
            int r = idx >> 4;
            int c = (idx & 15) * 8;
            uint4 v = make_uint4(0, 0, 0, 0);
            if (row0 + r < M)
                v = *(const uint4*)(Abf + (size_t)(row0 + r) * 128 + c);
            *(uint4*)&Hs[r * 136 + c] = v;
        }
    } else {
#pragma unroll
        for (int i = 0; i < 8; ++i) {
            int f4 = i * 256 + t;
            int r = f4 >> 5;
            int c4 = (f4 & 31) * 4;
            float4 v = make_float4(0.f, 0.f, 0.f, 0.f);
            if (row0 + r < M)
                v = ((const float4*)(A + (size_t)(row0 + r) * 128))[f4 & 31];
            ushort4 o;
            o.x = f2bfu(v.x); o.y = f2bfu(v.y); o.z = f2bfu(v.z); o.w = f2bfu(v.w);
            *(ushort4*)&Hs[r * 136 + c4] = o;
        }
    }
    __syncthreads();

    int kq = lane >> 4;
    int ln = lane & 15;

    f32x4 acc[2][4];
#pragma unroll
    for (int mt = 0; mt < 2; ++mt)
#pragma unroll
        for (int nt = 0; nt < 4; ++nt) {
            f32x4 z = {0.f, 0.f, 0.f, 0.f};
            acc[mt][nt] = z;
        }

#pragma unroll
    for (int ks = 0; ks < 4; ++ks) {
        bf16x8 bfr[4];
#pragma unroll
        for (int nt = 0; nt < 4; ++nt) {
            const uint4* p = (const uint4*)&Hs[(nt * 16 + ln) * 136 + ks * 32 + kq * 8];
            bfr[nt] = __builtin_bit_cast(bf16x8, *p);
        }
        bf16x8 afr[2];
#pragma unroll
        for (int mt = 0; mt < 2; ++mt) {
            int colA = w * 32 + mt * 16 + ln;
            afr[mt] = *(const bf16x8*)(Ppack + ((size_t)(ks * 4 + kq) * 128 + colA) * 8);
        }
#pragma unroll
        for (int mt = 0; mt < 2; ++mt)
#pragma unroll
            for (int nt = 0; nt < 4; ++nt)
                acc[mt][nt] = __builtin_amdgcn_mfma_f32_16x16x32_bf16(
                    afr[mt], bfr[nt], acc[mt][nt], 0, 0, 0);
    }

#pragma unroll
    for (int mt = 0; mt < 2; ++mt) {
        int col = w * 32 + mt * 16 + kq * 4;
        float4 bb = *(const float4*)(bp + col);
#pragma unroll
        for (int nt = 0; nt < 4; ++nt) {
            int node = row0 + nt * 16 + ln;
            if (node < M) {
                float4 o;
                o.x = fmaxf(acc[mt][nt][0] + bb.x, 0.f);
                o.y = fmaxf(acc[mt][nt][1] + bb.y, 0.f);
                o.z = fmaxf(acc[mt][nt][2] + bb.z, 0.f);
                o.w = fmaxf(acc[mt][nt][3] + bb.w, 0.f);
                *(float4*)(C + (size_t)node * 128 + col) = o;
            }
        }
    }
}

// ---------------------------------------------------------------------------
// FUSED score + segment-softmax + aggregate (online softmax, no atomics).
// v5: dependent-load chain shortened from 4 levels to 2 —
//   od[d] (fused offs+deg, one 8B load) -> srcs[...] (pre-gathered src ids)
//   -> fs row gather.
// ---------------------------------------------------------------------------
__global__ __launch_bounds__(256) void softagg_kernel(
    const unsigned short* __restrict__ fs, const unsigned short* __restrict__ fdp,
    const float* __restrict__ attn, const int2* __restrict__ od,
    const int* __restrict__ srcs, float* __restrict__ outf,
    unsigned short* __restrict__ eo)
{
    int d = blockIdx.x * 4 + (threadIdx.x >> 6);
    if (d >= NE_N) return;
    int l = threadIdx.x & 63;
    int2 rd = od[d];
    int r0 = rd.x;
    int n  = rd.y;
    int o = l * 8;

    uint4 fv = *(const uint4*)(fdp + (size_t)d * 512 + o);
    float fdv[8] = { blo(fv.x), bhi(fv.x), blo(fv.y), bhi(fv.y),
                     blo(fv.z), bhi(fv.z), blo(fv.w), bhi(fv.w) };
    float4 w0 = *(const float4*)(attn + o);
    float4 w1 = *(const float4*)(attn + o + 4);
    float wv[8] = { w0.x, w0.y, w0.z, w0.w, w1.x, w1.y, w1.z, w1.w };

    float m = -1e30f, sm = 0.f;
    float acc[8];
#pragma unroll
    for (int j = 0; j < 8; ++j) acc[j] = 0.f;

    for (int base = 0; base < n; base += 64) {
        int cnt = min(n - base, 64);
        int sl = 0;
        if (l < cnt) sl = srcs[r0 + base + l];
        for (int i = 0; i < cnt; ++i) {
            int s = __shfl(sl, i, 64);
            uint4 a = *(const uint4*)(fs + (size_t)s * 512 + o);
            float fsv[8] = { blo(a.x), bhi(a.x), blo(a.y), bhi(a.y),
                             blo(a.z), bhi(a.z), blo(a.w), bhi(a.w) };
            float p = 0.f;
#pragma unroll
            for (int j = 0; j < 8; ++j)
                p = fmaf(lrelu(fsv[j] + fdv[j]), wv[j], p);
#pragma unroll
            for (int mk = 1; mk < 16; mk <<= 1)
                p += __shfl_xor(p, mk, 64);
            float mn = fmaxf(m, p);
            float c  = __expf(m - mn);
            float av = __expf(p - mn);
            sm = sm * c + av;
            m = mn;
#pragma unroll
            for (int j = 0; j < 8; ++j)
                acc[j] = fmaf(av, fsv[j], acc[j] * c);
        }
    }

    float inv = (n > 0) ? 0.25f / sm : 0.f;
#pragma unroll
    for (int j = 0; j < 8; ++j) {
        float v = acc[j] * inv;
        v += __shfl_xor(v, 16, 64);
        v += __shfl_xor(v, 32, 64);
        acc[j] = v;
    }
    if (l < 16) {
        if (eo) {
            uint4 pk;
            pk.x = pk2(acc[0], acc[1]);
            pk.y = pk2(acc[2], acc[3]);
            pk.z = pk2(acc[4], acc[5]);
            pk.w = pk2(acc[6], acc[7]);
            *(uint4*)(eo + (size_t)d * 128 + l * 8) = pk;
        } else {
            float4 o0 = make_float4(acc[0], acc[1], acc[2], acc[3]);
            float4 o1 = make_float4(acc[4], acc[5], acc[6], acc[7]);
            *(float4*)(outf + (size_t)d * 128 + l * 8) = o0;
            *(float4*)(outf + (size_t)d * 128 + l * 8 + 4) = o1;
        }
    }
}

// ---------------------------------------------------------------------------
extern "C" void kernel_launch(void* const* d_in, const int* in_sizes, int n_in,
                              void* d_out, int out_size, void* d_ws, size_t ws_size,
                              hipStream_t stream)
{
    const float* v_feat = (const float*)d_in[0];
    const float* e_feat = (const float*)d_in[1];
    const float* Wv     = (const float*)d_in[2];
    const float* bv     = (const float*)d_in[3];
    const float* gv     = (const float*)d_in[4];
    const float* betav  = (const float*)d_in[5];
    const float* We     = (const float*)d_in[6];
    const float* be     = (const float*)d_in[7];
    const float* ge     = (const float*)d_in[8];
    const float* betae  = (const float*)d_in[9];
    const float* Wsrc   = (const float*)d_in[10];
    const float* bsrc   = (const float*)d_in[11];
    const float* Wdst   = (const float*)d_in[12];
    const float* bdst   = (const float*)d_in[13];
    const float* attn   = (const float*)d_in[14];
    const float* Wp     = (const float*)d_in[15];
    const float* bp     = (const float*)d_in[16];
    const int*   src    = (const int*)d_in[17];
    const int*   dst    = (const int*)d_in[18];
    float* out = (float*)d_out;

    unsigned short* fs = (unsigned short*)d_ws;
    unsigned short* fd = fs + (size_t)NPAD * 512;
    int* deg    = (int*)(fd + (size_t)NPAD * 512);
    int* offs   = deg + NE_N;
    int* cursor = offs + NE_N;
    int* bsum   = cursor + NE_N;
    int2* od    = (int2*)(bsum + 512);
    int* srcs   = (int*)(od + NE_N);
    bf16_t* pS  = (bf16_t*)(srcs + NEDGE);
    bf16_t* pD  = pS + 65536;
    bf16_t* pP  = pD + 65536;
    unsigned short* eo = (unsigned short*)(pP + 16384);

    size_t need = (size_t)((char*)(eo + (size_t)NE_N * 128) - (char*)d_ws);
    if (ws_size < need) eo = nullptr;   // f32 fallback path

    const int NB_SCAN = (NE_N + 255) / 256;   // 391

    // prep packs + zero deg (463 blocks: 72 pack + 391 zero)
    prep_kernel<<<463, 256, 0, stream>>>(Wsrc, Wdst, Wp, pS, pD, pP, deg);

    // CSR build
    count_kernel<<<(NEDGE + 255) / 256, 256, 0, stream>>>(dst, deg);
    scan1_kernel<<<NB_SCAN, 256, 0, stream>>>(deg, offs, bsum);
    scan2_kernel<<<1, 512, 0, stream>>>(bsum, NB_SCAN);
    scan3_kernel<<<NB_SCAN, 256, 0, stream>>>(offs, bsum, cursor, deg, od);
    scatter_kernel<<<(NEDGE + 255) / 256, 256, 0, stream>>>(dst, src, cursor, srcs);

    enc_proj_kernel<<<3126, 256, 0, stream>>>(
        v_feat, Wv, bv, gv, betav, pS, bsrc, fs,
        e_feat, We, be, ge, betae, pD, bdst, fd,
        1563, 100000);

    softagg_kernel<<<NE_N / 4, 256, 0, stream>>>(fs, fd, attn, od, srcs,
                                                 out, eo);

    final_gemm_kernel<<<1563, 256, 0, stream>>>(out, eo, pP, bp, out, NE_N);
}